// Round 1
// baseline (1585.786 us; speedup 1.0000x reference)
//
#include <hip/hip_runtime.h>

// B=4, S=2048, E=512, H=8. No softmax in reference -> fully linear:
//   out[b] = q~[b] * C~[b] + bo,  C~[b] = (1/E) sum_h U~[h] G~[b] Z~[h]^T
//   G~[b]=k~^T v~ [577ish], U~[h]=W~q^T W~k, Z~[h]=Wo_h W~v  (~ = bias-augmented, padded to 576)
// Total ~38 GFLOP of fp32 GEMMs. All tiles 64x64, K-step 32, no bounds checks
// (M,N multiples of 64; K multiples of 32). ws use: 18,137,088 floats = 72.5 MB.

typedef long long i64;

#define EB 512
#define EP 576          // augmented (513) padded to 9*64
#define SQ 2048
#define NB 4
#define NH 8
#define HEP (NH * EP)   // 4608

// ---------- TN with augmented columns: C[m,n] = sum_k A~[k,m] * B~[k,n]
// A~[k, m<512] = A[k*lda+m]; A~[k,512] = augA ? augA[k] : 1.0f; A~[k,>512] = 0
__global__ __launch_bounds__(256)
void gemm_tn_aug(const float* __restrict__ A, i64 lda, i64 sAz,
                 const float* __restrict__ augA, i64 sAugAz,
                 const float* __restrict__ B, i64 ldb, i64 sBz,
                 const float* __restrict__ augB, i64 sAugBz,
                 float* __restrict__ C, i64 ldc, i64 sCz,
                 int K)
{
    const int z = blockIdx.z;
    A += (i64)z * sAz;
    B += (i64)z * sBz;
    C += (i64)z * sCz;
    if (augA) augA += (i64)z * sAugAz;
    if (augB) augB += (i64)z * sAugBz;
    const int m0 = blockIdx.x * 64, n0 = blockIdx.y * 64;

    __shared__ float As[32][65];
    __shared__ float Bs[32][65];

    const int tid = threadIdx.x;
    const int tm = tid >> 4, tn = tid & 15;
    float acc[4][4] = {};

    for (int k0 = 0; k0 < K; k0 += 32) {
#pragma unroll
        for (int i = 0; i < 8; ++i) {
            const int e = tid + i * 256;
            const int kk = e >> 6, mm = e & 63;
            const int row = k0 + kk;
            const int ca = m0 + mm;
            As[kk][mm] = (ca < EB) ? A[(i64)row * lda + ca]
                         : (ca == EB ? (augA ? augA[row] : 1.0f) : 0.0f);
            const int cb = n0 + mm;
            Bs[kk][mm] = (cb < EB) ? B[(i64)row * ldb + cb]
                         : (cb == EB ? (augB ? augB[row] : 1.0f) : 0.0f);
        }
        __syncthreads();
#pragma unroll
        for (int kk = 0; kk < 32; ++kk) {
            float a[4], b[4];
#pragma unroll
            for (int i = 0; i < 4; ++i) a[i] = As[kk][tm * 4 + i];
#pragma unroll
            for (int j = 0; j < 4; ++j) b[j] = Bs[kk][tn * 4 + j];
#pragma unroll
            for (int i = 0; i < 4; ++i)
#pragma unroll
                for (int j = 0; j < 4; ++j)
                    acc[i][j] = fmaf(a[i], b[j], acc[i][j]);
        }
        __syncthreads();
    }
#pragma unroll
    for (int i = 0; i < 4; ++i) {
        const i64 m = m0 + tm * 4 + i;
#pragma unroll
        for (int j = 0; j < 4; ++j)
            C[m * ldc + (n0 + tn * 4 + j)] = acc[i][j];
    }
}

// ---------- NN (optionally B augmented), two optional row-broadcast biases
// C[m,n] = alpha * sum_k A[m,k] B~[k,n] + bias1[n] + bias2[n]
template <bool AUGB>
__global__ __launch_bounds__(256)
void gemm_nn(const float* __restrict__ A, i64 lda, i64 sA1, i64 sA2,
             const float* __restrict__ B, i64 ldb, i64 sB1, i64 sB2,
             const float* __restrict__ augB, i64 sAugB1,
             const float* __restrict__ bias1, i64 sBias1,
             const float* __restrict__ bias2,
             float* __restrict__ C, i64 ldc, i64 sC1, i64 sC2,
             int K, int zdiv, float alpha)
{
    const int z = blockIdx.z;
    const int z1 = z / zdiv, z2 = z % zdiv;
    A += (i64)z1 * sA1 + (i64)z2 * sA2;
    B += (i64)z1 * sB1 + (i64)z2 * sB2;
    C += (i64)z1 * sC1 + (i64)z2 * sC2;
    if (AUGB && augB) augB += (i64)z1 * sAugB1;
    if (bias1) bias1 += (i64)z1 * sBias1;
    const int m0 = blockIdx.x * 64, n0 = blockIdx.y * 64;

    __shared__ float As[32][65];
    __shared__ float Bs[32][65];

    const int tid = threadIdx.x;
    const int tm = tid >> 4, tn = tid & 15;
    const int lc = tid & 31, lr = tid >> 5;
    float acc[4][4] = {};

    for (int k0 = 0; k0 < K; k0 += 32) {
#pragma unroll
        for (int i = 0; i < 8; ++i) {
            const int r = lr + i * 8;
            As[lc][r] = A[(i64)(m0 + r) * lda + (k0 + lc)];
        }
#pragma unroll
        for (int i = 0; i < 8; ++i) {
            const int e = tid + i * 256;
            const int kk = e >> 6, nn = e & 63;
            const int cb = n0 + nn;
            float vb;
            if (AUGB) {
                vb = (cb < EB) ? B[(i64)(k0 + kk) * ldb + cb]
                     : (cb == EB ? augB[k0 + kk] : 0.0f);
            } else {
                vb = B[(i64)(k0 + kk) * ldb + cb];
            }
            Bs[kk][nn] = vb;
        }
        __syncthreads();
#pragma unroll
        for (int kk = 0; kk < 32; ++kk) {
            float a[4], b[4];
#pragma unroll
            for (int i = 0; i < 4; ++i) a[i] = As[kk][tm * 4 + i];
#pragma unroll
            for (int j = 0; j < 4; ++j) b[j] = Bs[kk][tn * 4 + j];
#pragma unroll
            for (int i = 0; i < 4; ++i)
#pragma unroll
                for (int j = 0; j < 4; ++j)
                    acc[i][j] = fmaf(a[i], b[j], acc[i][j]);
        }
        __syncthreads();
    }
#pragma unroll
    for (int i = 0; i < 4; ++i) {
        const i64 m = m0 + tm * 4 + i;
#pragma unroll
        for (int j = 0; j < 4; ++j) {
            const int n = n0 + tn * 4 + j;
            float vv = alpha * acc[i][j];
            if (bias1) vv += bias1[n];
            if (bias2) vv += bias2[n];
            C[m * ldc + n] = vv;
        }
    }
}

// ---------- NT: C[m,n] = alpha * sum_k A[m,k] * B[n,k]
__global__ __launch_bounds__(256)
void gemm_nt(const float* __restrict__ A, i64 lda, i64 sAz,
             const float* __restrict__ B, i64 ldb, i64 sBz,
             float* __restrict__ C, i64 ldc, i64 sCz,
             int K, float alpha)
{
    const int z = blockIdx.z;
    A += (i64)z * sAz;
    B += (i64)z * sBz;
    C += (i64)z * sCz;
    const int m0 = blockIdx.x * 64, n0 = blockIdx.y * 64;

    __shared__ float As[32][65];
    __shared__ float Bs[32][65];

    const int tid = threadIdx.x;
    const int tm = tid >> 4, tn = tid & 15;
    const int lc = tid & 31, lr = tid >> 5;
    float acc[4][4] = {};

    for (int k0 = 0; k0 < K; k0 += 32) {
#pragma unroll
        for (int i = 0; i < 8; ++i) {
            const int r = lr + i * 8;
            As[lc][r] = A[(i64)(m0 + r) * lda + (k0 + lc)];
            Bs[lc][r] = B[(i64)(n0 + r) * ldb + (k0 + lc)];
        }
        __syncthreads();
#pragma unroll
        for (int kk = 0; kk < 32; ++kk) {
            float a[4], b[4];
#pragma unroll
            for (int i = 0; i < 4; ++i) a[i] = As[kk][tm * 4 + i];
#pragma unroll
            for (int j = 0; j < 4; ++j) b[j] = Bs[kk][tn * 4 + j];
#pragma unroll
            for (int i = 0; i < 4; ++i)
#pragma unroll
                for (int j = 0; j < 4; ++j)
                    acc[i][j] = fmaf(a[i], b[j], acc[i][j]);
        }
        __syncthreads();
    }
#pragma unroll
    for (int i = 0; i < 4; ++i) {
        const i64 m = m0 + tm * 4 + i;
#pragma unroll
        for (int j = 0; j < 4; ++j)
            C[m * ldc + (n0 + tn * 4 + j)] = alpha * acc[i][j];
    }
}

extern "C" void kernel_launch(void* const* d_in, const int* in_sizes, int n_in,
                              void* d_out, int out_size, void* d_ws, size_t ws_size,
                              hipStream_t stream)
{
    const float* q  = (const float*)d_in[0];
    const float* k  = (const float*)d_in[1];
    const float* v  = (const float*)d_in[2];
    const float* Wq = (const float*)d_in[3];
    const float* bq = (const float*)d_in[4];
    const float* Wk = (const float*)d_in[5];
    const float* bk = (const float*)d_in[6];
    const float* Wv = (const float*)d_in[7];
    const float* bv = (const float*)d_in[8];
    const float* Wo = (const float*)d_in[9];
    const float* bo = (const float*)d_in[10];
    float* out = (float*)d_out;

    float* ws = (float*)d_ws;
    float* Ut = ws;                         // 8*576*576   = 2,654,208
    float* Zt = Ut + (i64)NH * EP * EP;     // 512*4608    = 2,359,296
    float* Gt = Zt + (i64)EB * HEP;         // 4*576*576   = 1,327,104
    float* H1 = Gt + (i64)NB * EP * EP;     // 4*576*4608  = 10,616,832
    float* Ct = H1 + (i64)NB * EP * HEP;    // 4*576*512   = 1,179,648
    (void)ws_size; (void)in_sizes; (void)n_in; (void)out_size;

    dim3 blk(256);

    // U~[h] = W~q[h]^T W~k[h]   [576x576], K=512
    gemm_tn_aug<<<dim3(9, 9, NH), blk, 0, stream>>>(
        Wq, EB, (i64)EB * EB, bq, EB,
        Wk, EB, (i64)EB * EB, bk, EB,
        Ut, EP, (i64)EP * EP, EB);

    // Z~[h] = Wo_h W~v[h]  -> Zt[512][4608] at col h*576, K=512
    gemm_nn<true><<<dim3(8, 9, NH), blk, 0, stream>>>(
        Wo, (i64)NH * EB, EB, 0,
        Wv, EB, (i64)EB * EB, 0,
        bv, EB,
        nullptr, 0, nullptr,
        Zt, HEP, EP, 0,
        EB, 1, 1.0f);

    // G~[b] = k~[b]^T v~[b]   [576x576], K=2048
    gemm_tn_aug<<<dim3(9, 9, NB), blk, 0, stream>>>(
        k, EB, (i64)SQ * EB, nullptr, 0,
        v, EB, (i64)SQ * EB, nullptr, 0,
        Gt, EP, (i64)EP * EP, SQ);

    // H1[b,h] = U~[h] G~[b] -> H1[b][576][4608] at col h*576, K=576
    gemm_nn<false><<<dim3(9, 9, NB * NH), blk, 0, stream>>>(
        Ut, EP, 0, (i64)EP * EP,
        Gt, EP, (i64)EP * EP, 0,
        nullptr, 0,
        nullptr, 0, nullptr,
        H1, HEP, (i64)EP * HEP, EP,
        EP, NH, 1.0f);

    // C~[b] = (1/512) * H1[b] * Zt^T   [576x512], K=4608
    gemm_nt<<<dim3(9, 8, NB), blk, 0, stream>>>(
        H1, HEP, (i64)EP * HEP,
        Zt, HEP, 0,
        Ct, EB, (i64)EP * EB,
        HEP, 1.0f / 512.0f);

    // out[b] = q[b] * C~[b][0:512,:] + C~[b][512,:] + bo   [2048x512], K=512
    gemm_nn<false><<<dim3(32, 8, NB), blk, 0, stream>>>(
        q, EB, (i64)SQ * EB, 0,
        Ct, EB, (i64)EP * EB, 0,
        nullptr, 0,
        Ct + (i64)EB * EB, (i64)EP * EB,
        bo,
        out, EB, (i64)SQ * EB, 0,
        EB, 1, 1.0f);
}

// Round 2
// 322.806 us; speedup vs baseline: 4.9125x; 4.9125x over previous
//
#include <hip/hip_runtime.h>

// B=4, S=2048, E=512, H=8. Linear "attention" (no softmax) collapsed to:
//   out[b] = q~[b] * C~[b] + bo,  C~[b] = (1/512) sum_h U~[h] G~[b] Z~[h]^T
// Augmented dim 513 padded to 640 (=5*128) so all GEMMs are 128x128-tile
// NT bf16 MFMA (C = A * B^T, A [MxK] rm, B [NxK] rm), fp32 accumulate.
// m97 structure: global_load_lds w16, pre-swizzled source, swizzled ds_read_b128.

typedef long long i64;
typedef unsigned short u16;
typedef __attribute__((ext_vector_type(8))) short bf16x8;
typedef __attribute__((ext_vector_type(4))) float f32x4;

#define EB 512
#define EP 640
#define SQ 2048
#define NB 4
#define NH 8
#define HEP (NH * EP)   // 5120

__device__ __forceinline__ u16 f2bf(float x) {
    unsigned u = __float_as_uint(x);
    return (u16)((u + 0x7fffu + ((u >> 16) & 1u)) >> 16);
}

__device__ __forceinline__ void gload16(const void* g, void* l) {
    __builtin_amdgcn_global_load_lds(
        (const __attribute__((address_space(1))) unsigned int*)g,
        (__attribute__((address_space(3))) unsigned int*)l, 16, 0, 0);
}

// ---------------- NT bf16 MFMA GEMM, 128x128 tile, BK=64 ----------------
// EPI 0: bf16 store. EPI 1: fp32 atomicAdd (split-K). EPI 2: fp32 store +
// rowbias (CT_f32[., col*640+512] / 512) + bo[col]   (final stage).
template <int EPI>
__global__ __launch_bounds__(256)
void gemm_nt_bf16(const u16* __restrict__ A, i64 lda, i64 sA1, i64 sA2,
                  const u16* __restrict__ B, i64 ldb, i64 sB1, i64 sB2,
                  void* __restrict__ Cv, i64 ldc, i64 sC1, i64 sC2,
                  int K, int zdiv,
                  const float* __restrict__ rbias, i64 sRB,
                  const float* __restrict__ bo)
{
    __shared__ __align__(16) char lA[16384];
    __shared__ __align__(16) char lB[16384];
    const int z = blockIdx.z, z1 = z / zdiv, z2 = z % zdiv;
    A += (i64)z1 * sA1 + (i64)z2 * sA2;
    B += (i64)z1 * sB1 + (i64)z2 * sB2;
    const i64 m0 = (i64)blockIdx.x * 128, n0 = (i64)blockIdx.y * 128;
    const int tid = threadIdx.x, lane = tid & 63, wid = tid >> 6;
    const int wr = wid >> 1, wc = wid & 1;
    const int g = lane >> 4, li = lane & 15;

    // staging: 16 chunks of 1024B per operand tile; chunk c covers rows c*8..c*8+7.
    // LDS dest is linear (wave-uniform base + lane*16); global source col-chunk is
    // pre-swizzled so that swizzled ds_reads see the right data.
    i64 offA[4], offB[4]; int lofs[4];
#pragma unroll
    for (int i = 0; i < 4; ++i) {
        const int chunk = i * 4 + wid;
        const int rr = chunk * 8 + (lane >> 3);
        const int gc = ((lane & 7) ^ (rr & 7)) << 3;   // pre-swizzled col chunk (elements)
        offA[i] = (m0 + rr) * lda + gc;
        offB[i] = (n0 + rr) * ldb + gc;
        lofs[i] = chunk * 1024;
    }

    f32x4 acc[4][4];
#pragma unroll
    for (int a_ = 0; a_ < 4; ++a_)
#pragma unroll
        for (int b_ = 0; b_ < 4; ++b_) acc[a_][b_] = (f32x4){0.f, 0.f, 0.f, 0.f};

    const int nIt = K >> 6;
    for (int it = 0; it < nIt; ++it) {
        const i64 k0 = (i64)it << 6;
#pragma unroll
        for (int i = 0; i < 4; ++i) {
            gload16(A + offA[i] + k0, lA + lofs[i]);
            gload16(B + offB[i] + k0, lB + lofs[i]);
        }
        __syncthreads();   // drains vmcnt before barrier (compiler-inserted)
#pragma unroll
        for (int ks = 0; ks < 2; ++ks) {
            bf16x8 af[4], bfr[4];
#pragma unroll
            for (int f = 0; f < 4; ++f) {
                const int row = wr * 64 + f * 16 + li;
                const int slot = (ks * 4 + g) ^ (row & 7);
                af[f] = *(const bf16x8*)(lA + row * 128 + slot * 16);
            }
#pragma unroll
            for (int f = 0; f < 4; ++f) {
                const int row = wc * 64 + f * 16 + li;
                const int slot = (ks * 4 + g) ^ (row & 7);
                bfr[f] = *(const bf16x8*)(lB + row * 128 + slot * 16);
            }
#pragma unroll
            for (int fm = 0; fm < 4; ++fm)
#pragma unroll
                for (int fn = 0; fn < 4; ++fn)
                    acc[fm][fn] = __builtin_amdgcn_mfma_f32_16x16x32_bf16(
                        af[fm], bfr[fn], acc[fm][fn], 0, 0, 0);
        }
        __syncthreads();
    }

    if (EPI == 0) {
        u16* C = (u16*)Cv + (i64)z1 * sC1 + (i64)z2 * sC2;
#pragma unroll
        for (int fm = 0; fm < 4; ++fm)
#pragma unroll
            for (int fn = 0; fn < 4; ++fn) {
                const i64 col = n0 + wc * 64 + fn * 16 + li;
#pragma unroll
                for (int q = 0; q < 4; ++q) {
                    const i64 row = m0 + wr * 64 + fm * 16 + g * 4 + q;
                    C[row * ldc + col] = f2bf(acc[fm][fn][q]);
                }
            }
    } else if (EPI == 1) {
        float* C = (float*)Cv + (i64)z1 * sC1 + (i64)z2 * sC2;
#pragma unroll
        for (int fm = 0; fm < 4; ++fm)
#pragma unroll
            for (int fn = 0; fn < 4; ++fn) {
                const i64 col = n0 + wc * 64 + fn * 16 + li;
#pragma unroll
                for (int q = 0; q < 4; ++q) {
                    const i64 row = m0 + wr * 64 + fm * 16 + g * 4 + q;
                    atomicAdd(&C[row * ldc + col], acc[fm][fn][q]);
                }
            }
    } else {
        float* C = (float*)Cv + (i64)z1 * sC1;
#pragma unroll
        for (int fn = 0; fn < 4; ++fn) {
            const i64 col = n0 + wc * 64 + fn * 16 + li;
            const float bb = rbias[(i64)z1 * sRB + col * 640 + 512] * (1.0f / 512.0f)
                             + bo[col];
#pragma unroll
            for (int fm = 0; fm < 4; ++fm)
#pragma unroll
                for (int q = 0; q < 4; ++q) {
                    const i64 row = m0 + wr * 64 + fm * 16 + g * 4 + q;
                    C[row * ldc + col] = acc[fm][fn][q] + bb;
                }
        }
    }
}

// ------------- transpose + convert + augment: src f32 [Sx512] -> dst bf16 [640xS]
// dst[e,s] = src[s,e] (e<512); dst[512,s] = aug ? aug[s] : 1.0; dst[e>512,s] = 0.
__global__ __launch_bounds__(256)
void transpose_aug(const float* __restrict__ src, i64 sSrc,
                   const float* __restrict__ aug, i64 sAug,
                   u16* __restrict__ dst, i64 sDst, int S)
{
    const int z = blockIdx.z;
    src += (i64)z * sSrc;
    dst += (i64)z * sDst;
    if (aug) aug += (i64)z * sAug;
    const int s0 = blockIdx.x * 64, e0 = blockIdx.y * 64;
    const int t = threadIdx.x;

    if (e0 >= EB) {
#pragma unroll
        for (int i = 0; i < 16; ++i) {
            const int idx = i * 256 + t;
            const int er = idx >> 6, sc = idx & 63;
            const int e = e0 + er;
            u16 val = 0;
            if (e == EB) val = f2bf(aug ? aug[s0 + sc] : 1.0f);
            dst[(i64)e * S + s0 + sc] = val;
        }
        return;
    }
    __shared__ float tile[64][65];
#pragma unroll
    for (int i = 0; i < 16; ++i) {
        const int idx = i * 256 + t;
        const int sr = idx >> 6, ec = idx & 63;
        tile[sr][ec] = src[(i64)(s0 + sr) * EB + e0 + ec];
    }
    __syncthreads();
#pragma unroll
    for (int i = 0; i < 16; ++i) {
        const int idx = i * 256 + t;
        const int er = idx >> 6, sc = idx & 63;
        dst[(i64)(e0 + er) * S + s0 + sc] = f2bf(tile[sc][er]);
    }
}

// ------------- elementwise f32 -> bf16 (scaled) -------------
__global__ __launch_bounds__(256)
void cvt_bf16(const float4* __restrict__ in, ushort4* __restrict__ outp,
              float alpha, i64 n4)
{
    const i64 i = (i64)blockIdx.x * 256 + threadIdx.x;
    if (i >= n4) return;
    const float4 v = in[i];
    ushort4 o;
    o.x = f2bf(v.x * alpha); o.y = f2bf(v.y * alpha);
    o.z = f2bf(v.z * alpha); o.w = f2bf(v.w * alpha);
    outp[i] = o;
}

extern "C" void kernel_launch(void* const* d_in, const int* in_sizes, int n_in,
                              void* d_out, int out_size, void* d_ws, size_t ws_size,
                              hipStream_t stream)
{
    const float* q  = (const float*)d_in[0];
    const float* k  = (const float*)d_in[1];
    const float* v  = (const float*)d_in[2];
    const float* Wq = (const float*)d_in[3];
    const float* bq = (const float*)d_in[4];
    const float* Wk = (const float*)d_in[5];
    const float* bk = (const float*)d_in[6];
    const float* Wv = (const float*)d_in[7];
    const float* bv = (const float*)d_in[8];
    const float* Wo = (const float*)d_in[9];
    const float* bo = (const float*)d_in[10];
    float* out = (float*)d_out;
    (void)in_sizes; (void)n_in; (void)out_size; (void)ws_size;

    char* ws = (char*)d_ws;
    // byte offsets (all 1KB aligned); phase-aliased regions:
    u16*   qb     = (u16*)(ws + 0);                    //  8,388,608  bf16 q
    u16*   kT     = (u16*)(ws + 8388608);              // 10,485,760  [b][640][2048]
    u16*   vT     = (u16*)(ws + 18874368);             // 10,485,760
    u16*   Hcat   = (u16*)(ws + 8388608);              // 26,214,400  aliases kT/vT (dead)
    u16*   WqT    = (u16*)(ws + 34603008);             //  5,242,880  [h][640][512]
    u16*   WkT    = (u16*)(ws + 39845888);             //  5,242,880
    u16*   WvT    = (u16*)(ws + 45088768);             //  5,242,880
    float* CTf    = (float*)(ws + 34603008);           //  5,242,880  aliases WqT (dead)
    u16*   CTb    = (u16*)(ws + 39845888);             //  2,621,440  aliases WkT (dead)
    u16*   Wob    = (u16*)(ws + 50331648);             //  4,194,304  bf16 Wo [512x4096]
    u16*   GTb    = (u16*)(ws + 50331648);             //  3,276,800  aliases Wob (dead)
    u16*   U      = (u16*)(ws + 54525952);             //  6,553,600  [h][640][640]
    u16*   Zcat   = (u16*)(ws + 61079552);             //  5,242,880  [512][5120]
    float* GTf    = (float*)(ws + 66322432);           //  6,553,600  [b][640][640]
    // total 72,876,032 bytes

    const dim3 blk(256);

    // ---- prep: converts + transposes ----
    cvt_bf16<<<dim3(4096), blk, 0, stream>>>((const float4*)q, (ushort4*)qb, 1.0f,
                                             (i64)NB * SQ * EB / 4);
    cvt_bf16<<<dim3(2048), blk, 0, stream>>>((const float4*)Wo, (ushort4*)Wob, 1.0f,
                                             (i64)EB * NH * EB / 4);
    transpose_aug<<<dim3(32, 10, NB), blk, 0, stream>>>(k, (i64)SQ * EB, nullptr, 0,
                                                        kT, (i64)EP * SQ, SQ);
    transpose_aug<<<dim3(32, 10, NB), blk, 0, stream>>>(v, (i64)SQ * EB, nullptr, 0,
                                                        vT, (i64)EP * SQ, SQ);
    transpose_aug<<<dim3(8, 10, NH), blk, 0, stream>>>(Wq, (i64)EB * EB, bq, EB,
                                                       WqT, (i64)EP * EB, EB);
    transpose_aug<<<dim3(8, 10, NH), blk, 0, stream>>>(Wk, (i64)EB * EB, bk, EB,
                                                       WkT, (i64)EP * EB, EB);
    transpose_aug<<<dim3(8, 10, NH), blk, 0, stream>>>(Wv, (i64)EB * EB, bv, EB,
                                                       WvT, (i64)EP * EB, EB);
    hipMemsetAsync(GTf, 0, (i64)NB * EP * EP * 4, stream);

    // ---- U[h] = W~q[h]^T W~k[h] : NT(WqT, WkT), K=512 -> bf16 [640x640]
    gemm_nt_bf16<0><<<dim3(5, 5, NH), blk, 0, stream>>>(
        WqT, EB, (i64)EP * EB, 0,
        WkT, EB, (i64)EP * EB, 0,
        U, EP, (i64)EP * EP, 0,
        EB, 1, nullptr, 0, nullptr);

    // ---- Z[h] = Wo_h W~v[h] : NT(Wo_b + h*512 (ld 4096), WvT), K=512 -> Zcat col h*640
    gemm_nt_bf16<0><<<dim3(4, 5, NH), blk, 0, stream>>>(
        Wob, (i64)NH * EB, EB, 0,
        WvT, EB, (i64)EP * EB, 0,
        Zcat, HEP, EP, 0,
        EB, 1, nullptr, 0, nullptr);

    // ---- GT[b] = v~^T-stack: NT(vT, kT), K=2048 split 4x512 -> atomic f32
    gemm_nt_bf16<1><<<dim3(5, 5, NB * 4), blk, 0, stream>>>(
        vT, SQ, (i64)EP * SQ, EB,
        kT, SQ, (i64)EP * SQ, EB,
        GTf, EP, (i64)EP * EP, 0,
        EB, 4, nullptr, 0, nullptr);

    cvt_bf16<<<dim3(1600), blk, 0, stream>>>((const float4*)GTf, (ushort4*)GTb, 1.0f,
                                             (i64)NB * EP * EP / 4);

    // ---- H[b,h] = U[h] * G[b] : NT(U[h], GTb[b]), K=640 -> Hcat[b] col h*640
    gemm_nt_bf16<0><<<dim3(5, 5, NB * NH), blk, 0, stream>>>(
        U, EP, 0, (i64)EP * EP,
        GTb, EP, (i64)EP * EP, 0,
        Hcat, HEP, (i64)EP * HEP, EP,
        EP, NH, nullptr, 0, nullptr);

    hipMemsetAsync(CTf, 0, (i64)NB * EB * EP * 4, stream);

    // ---- CT[b] = NT(Zcat, Hcat[b]), K=5120 split 8x640 -> atomic f32 [512x640]
    gemm_nt_bf16<1><<<dim3(4, 5, NB * 8), blk, 0, stream>>>(
        Zcat, HEP, 0, EP,
        Hcat, HEP, (i64)EP * HEP, EP,
        CTf, EP, (i64)EB * EP, 0,
        EP, 8, nullptr, 0, nullptr);

    cvt_bf16<<<dim3(1280), blk, 0, stream>>>((const float4*)CTf, (ushort4*)CTb,
                                             1.0f / 512.0f, (i64)NB * EB * EP / 4);

    // ---- out[b] = NT(qb, CTb cols 0..511) + CTf[.,col*640+512]/512 + bo
    gemm_nt_bf16<2><<<dim3(16, 4, NB), blk, 0, stream>>>(
        qb, EB, (i64)SQ * EB, 0,
        CTb, EP, (i64)EB * EP, 0,
        out, EB, (i64)SQ * EB, 0,
        EB, 1, CTf, (i64)EB * EP, bo);
}

// Round 3
// 287.598 us; speedup vs baseline: 5.5139x; 1.1224x over previous
//
#include <hip/hip_runtime.h>

// B=4,S=2048,E=512,H=8. Linear attention (no softmax) collapsed to GEMM chain:
//  out[b] = q~[b]*C~[b]+bo,  C~[b]=(1/512) sum_h U~[h] G~[b] Z~[h]^T
// Reordered: ZG[b,h]=Z~[h]*G~[b]^T, CT[b]=ZGcat[b]*Ucat^T (K=5120). ~44 GF bf16.
// All GEMMs: NT 128x128 tile, BK=64, 2-phase double-buffered global_load_lds(16B),
// pre-swizzled source + XOR-swizzled ds_read_b128, 16x16x32 bf16 MFMA, fp32 acc.

typedef long long i64;
typedef unsigned short u16;
typedef __attribute__((ext_vector_type(8))) short bf16x8;
typedef __attribute__((ext_vector_type(4))) float f32x4;

#define EB 512
#define EP 640
#define SQ 2048
#define NB 4
#define NH 8
#define HEP 5120

// ---- workspace byte offsets (total 70,909,952 <= proven ws budget) ----
#define OFF_QB    0ll          //  8,388,608  bf16 q [4][2048][512]
#define OFF_KT    8388608ll    // 10,485,760  bf16 kT [4][640][2048]
#define OFF_VT    18874368ll   // 10,485,760  bf16 vT
#define OFF_WQT   29360128ll   //  5,242,880  bf16 WqT [8][640][512]
#define OFF_WKT   34603008ll   //  5,242,880
#define OFF_WVT   39845888ll   //  5,242,880
#define OFF_WOB   45088768ll   //  4,194,304  bf16 Wo [512][4096]
#define OFF_UCAT  49283072ll   //  6,553,600  bf16 Ucat [640][5120]
#define OFF_ZCAT  55836672ll   //  5,242,880  bf16 Zcat [512][5120]
#define OFF_GF    61079552ll   //  6,553,600  f32 Gf [4][640][640] (atomic)
#define OFF_GB    67633152ll   //  3,276,800  bf16 Gb [4][640][640]
#define OFF_ZGC   8388608ll    // 20,971,520  bf16 ZGcat [4][512][5120] (alias kT+vT)
#define OFF_CTF   29360128ll   //  5,242,880  f32 CTf [4][512][640] (alias WqT)
#define OFF_CTB   34603008ll   //  2,621,440  bf16 CTb [4][512][640] (alias WkT)

__device__ __forceinline__ u16 f2bf(float x) {
    unsigned u = __float_as_uint(x);
    return (u16)((u + 0x7fffu + ((u >> 16) & 1u)) >> 16);
}

__device__ __forceinline__ void gload16(const void* g, void* l) {
    __builtin_amdgcn_global_load_lds(
        (const __attribute__((address_space(1))) unsigned int*)g,
        (__attribute__((address_space(3))) unsigned int*)l, 16, 0, 0);
}

// =============== shared GEMM body: C = A * B^T, 128x128 tile, BK=64 ===============
// epi 0: bf16 store to (u16*)C. epi 1: f32 atomicAdd. epi 2: f32 store + rbias+bo.
__device__ __forceinline__ void gemm_body(
    const u16* __restrict__ A, i64 lda, const u16* __restrict__ B, i64 ldb,
    int bx, int by, int K, int epi, void* Cv, i64 ldc,
    const float* rbias, const float* bo,
    char* lA0, char* lA1, char* lB0, char* lB1)
{
    const i64 m0 = (i64)bx * 128, n0 = (i64)by * 128;
    const int tid = threadIdx.x, lane = tid & 63, wid = tid >> 6;
    const int wr = wid >> 1, wc = wid & 1;
    const int g = lane >> 4, li = lane & 15;

    i64 offA[4], offB[4]; int lofs[4];
#pragma unroll
    for (int i = 0; i < 4; ++i) {
        const int chunk = i * 4 + wid;
        const int rr = chunk * 8 + (lane >> 3);
        const int gc = ((lane & 7) ^ (rr & 7)) << 3;   // pre-swizzled col chunk
        offA[i] = (m0 + rr) * lda + gc;
        offB[i] = (n0 + rr) * ldb + gc;
        lofs[i] = chunk * 1024 + (lane & 7) * 0;       // dest = chunk*1024 + lane*16 (in gload)
        lofs[i] = chunk * 1024;
    }
    // NOTE: gload16 dest is wave-uniform base + lane*16; we pass base+lane*16 manually:
    const int ldest = (lane) * 16;

    f32x4 acc[4][4];
#pragma unroll
    for (int a_ = 0; a_ < 4; ++a_)
#pragma unroll
        for (int b_ = 0; b_ < 4; ++b_) acc[a_][b_] = (f32x4){0.f, 0.f, 0.f, 0.f};

    char* bufA[2] = {lA0, lA1};
    char* bufB[2] = {lB0, lB1};
    const int nIt = K >> 6;

    // prologue: stage tile 0 into buf 0
#pragma unroll
    for (int i = 0; i < 4; ++i) {
        gload16(A + offA[i], bufA[0] + lofs[i] + ldest);
        gload16(B + offB[i], bufB[0] + lofs[i] + ldest);
    }
    __syncthreads();

    int cur = 0;
    for (int it = 0; it < nIt; ++it) {
        if (it + 1 < nIt) {
            const i64 k0 = (i64)(it + 1) << 6;
#pragma unroll
            for (int i = 0; i < 4; ++i) {
                gload16(A + offA[i] + k0, bufA[cur ^ 1] + lofs[i] + ldest);
                gload16(B + offB[i] + k0, bufB[cur ^ 1] + lofs[i] + ldest);
            }
        }
        char* cA = bufA[cur];
        char* cB = bufB[cur];
#pragma unroll
        for (int ks = 0; ks < 2; ++ks) {
            bf16x8 af[4], bfr[4];
#pragma unroll
            for (int f = 0; f < 4; ++f) {
                const int row = wr * 64 + f * 16 + li;
                const int slot = (ks * 4 + g) ^ (row & 7);
                af[f] = *(const bf16x8*)(cA + row * 128 + slot * 16);
            }
#pragma unroll
            for (int f = 0; f < 4; ++f) {
                const int row = wc * 64 + f * 16 + li;
                const int slot = (ks * 4 + g) ^ (row & 7);
                bfr[f] = *(const bf16x8*)(cB + row * 128 + slot * 16);
            }
#pragma unroll
            for (int fm = 0; fm < 4; ++fm)
#pragma unroll
                for (int fn = 0; fn < 4; ++fn)
                    acc[fm][fn] = __builtin_amdgcn_mfma_f32_16x16x32_bf16(
                        af[fm], bfr[fn], acc[fm][fn], 0, 0, 0);
        }
        __syncthreads();
        cur ^= 1;
    }

    if (epi == 0) {
        u16* C = (u16*)Cv;
#pragma unroll
        for (int fm = 0; fm < 4; ++fm)
#pragma unroll
            for (int fn = 0; fn < 4; ++fn) {
                const i64 col = n0 + wc * 64 + fn * 16 + li;
#pragma unroll
                for (int q = 0; q < 4; ++q) {
                    const i64 row = m0 + wr * 64 + fm * 16 + g * 4 + q;
                    C[row * ldc + col] = f2bf(acc[fm][fn][q]);
                }
            }
    } else if (epi == 1) {
        float* C = (float*)Cv;
#pragma unroll
        for (int fm = 0; fm < 4; ++fm)
#pragma unroll
            for (int fn = 0; fn < 4; ++fn) {
                const i64 col = n0 + wc * 64 + fn * 16 + li;
#pragma unroll
                for (int q = 0; q < 4; ++q) {
                    const i64 row = m0 + wr * 64 + fm * 16 + g * 4 + q;
                    atomicAdd(&C[row * ldc + col], acc[fm][fn][q]);
                }
            }
    } else {
        float* C = (float*)Cv;
#pragma unroll
        for (int fn = 0; fn < 4; ++fn) {
            const i64 col = n0 + wc * 64 + fn * 16 + li;
            const float bb = rbias[col * 640 + 512] * (1.0f / 512.0f) + bo[col];
#pragma unroll
            for (int fm = 0; fm < 4; ++fm)
#pragma unroll
                for (int q = 0; q < 4; ++q) {
                    const i64 row = m0 + wr * 64 + fm * 16 + g * 4 + q;
                    C[row * ldc + col] = acc[fm][fn][q] + bb;
                }
        }
    }
}

#define GEMM_LDS \
    __shared__ __align__(16) char lA0[16384], lA1[16384]; \
    __shared__ __align__(16) char lB0[16384], lB1[16384];

// =============== stage 1 fused: U (200) + Z (160) + G split-4 (400) ===============
__global__ __launch_bounds__(256)
void gemm_stage1(char* __restrict__ ws)
{
    GEMM_LDS
    const int b = blockIdx.x;
    const u16* A; const u16* B; i64 lda, ldb, ldc; void* C;
    int bx, by, K, epi;
    if (b < 200) {            // U[h] = W~q^T W~k -> Ucat[640][5120] col h*640
        const int h = b / 25, r = b % 25;
        bx = r / 5; by = r % 5;
        A = (const u16*)(ws + OFF_WQT) + (i64)h * EP * EB; lda = EB;
        B = (const u16*)(ws + OFF_WKT) + (i64)h * EP * EB; ldb = EB;
        C = (u16*)(ws + OFF_UCAT) + (i64)h * EP; ldc = HEP;
        K = EB; epi = 0;
    } else if (b < 360) {     // Z[h] = Wo_h W~v -> Zcat[512][5120] col h*640
        const int t = b - 200, h = t / 20, r = t % 20;
        bx = r / 5; by = r % 5;
        A = (const u16*)(ws + OFF_WOB) + (i64)h * EB; lda = (i64)NH * EB;
        B = (const u16*)(ws + OFF_WVT) + (i64)h * EP * EB; ldb = EB;
        C = (u16*)(ws + OFF_ZCAT) + (i64)h * EP; ldc = HEP;
        K = EB; epi = 0;
    } else {                  // G[b] = k~^T v~ (K=2048 split 4) -> atomic f32 Gf
        const int t = b - 360, zz = t / 25, r = t % 25;
        bx = r / 5; by = r % 5;
        const int bb = zz >> 2, sp = zz & 3;
        A = (const u16*)(ws + OFF_KT) + (i64)bb * EP * SQ + (i64)sp * EB; lda = SQ;
        B = (const u16*)(ws + OFF_VT) + (i64)bb * EP * SQ + (i64)sp * EB; ldb = SQ;
        C = (float*)(ws + OFF_GF) + (i64)bb * EP * EP; ldc = EP;
        K = EB; epi = 1;
    }
    gemm_body(A, lda, B, ldb, bx, by, K, epi, C, ldc, nullptr, nullptr,
              lA0, lA1, lB0, lB1);
}

// =============== stage 2: ZG[b,h] = Z[h] * G[b]^T -> ZGcat[b][512][5120] ===============
__global__ __launch_bounds__(256)
void gemm_zg(char* __restrict__ ws)
{
    GEMM_LDS
    const int z = blockIdx.z, bb = z >> 3, h = z & 7;
    const u16* A = (const u16*)(ws + OFF_ZCAT) + (i64)h * EP;
    const u16* B = (const u16*)(ws + OFF_GB) + (i64)bb * EP * EP;
    u16* C = (u16*)(ws + OFF_ZGC) + (i64)bb * EB * HEP + (i64)h * EP;
    gemm_body(A, HEP, B, EP, blockIdx.x, blockIdx.y, EP, 0, C, HEP,
              nullptr, nullptr, lA0, lA1, lB0, lB1);
}

// =============== stage 3: CT[b] = ZGcat[b] * Ucat^T (K=5120 split 8, atomic) ===============
__global__ __launch_bounds__(256)
void gemm_ct(char* __restrict__ ws)
{
    GEMM_LDS
    const int z = blockIdx.z, bb = z >> 3, sp = z & 7;
    const u16* A = (const u16*)(ws + OFF_ZGC) + (i64)bb * EB * HEP + (i64)sp * EP;
    const u16* B = (const u16*)(ws + OFF_UCAT) + (i64)sp * EP;
    float* C = (float*)(ws + OFF_CTF) + (i64)bb * EB * EP;
    gemm_body(A, HEP, B, HEP, blockIdx.x, blockIdx.y, EP, 1, C, EP,
              nullptr, nullptr, lA0, lA1, lB0, lB1);
}

// =============== stage 4: out[b] = qb[b]*CTb[b]^T + rbias + bo ===============
__global__ __launch_bounds__(256)
void gemm_out(char* __restrict__ ws, float* __restrict__ out,
              const float* __restrict__ bo)
{
    GEMM_LDS
    const int bb = blockIdx.z;
    const u16* A = (const u16*)(ws + OFF_QB) + (i64)bb * SQ * EB;
    const u16* B = (const u16*)(ws + OFF_CTB) + (i64)bb * EB * EP;
    float* C = out + (i64)bb * SQ * EB;
    const float* rb = (const float*)(ws + OFF_CTF) + (i64)bb * EB * EP;
    gemm_body(A, EB, B, EP, blockIdx.x, blockIdx.y, EB, 2, C, EB,
              rb, bo, lA0, lA1, lB0, lB1);
}

// =============== transpose+aug device helper (f32 [Sx512] -> bf16 [640xS]) ===============
__device__ __forceinline__ void transpose_dev(
    const float* __restrict__ src, const float* __restrict__ aug,
    u16* __restrict__ dst, int S, int bx, int by)
{
    const int s0 = bx * 64, e0 = by * 64;
    const int t = threadIdx.x;
    if (e0 >= EB) {
#pragma unroll
        for (int i = 0; i < 16; ++i) {
            const int idx = i * 256 + t;
            const int er = idx >> 6, sc = idx & 63;
            const int e = e0 + er;
            u16 val = 0;
            if (e == EB) val = f2bf(aug ? aug[s0 + sc] : 1.0f);
            dst[(i64)e * S + s0 + sc] = val;
        }
        return;
    }
    __shared__ float tile[64][65];
#pragma unroll
    for (int i = 0; i < 16; ++i) {
        const int idx = i * 256 + t;
        const int sr = idx >> 6, ec = idx & 63;
        tile[sr][ec] = src[(i64)(s0 + sr) * EB + e0 + ec];
    }
    __syncthreads();
#pragma unroll
    for (int i = 0; i < 16; ++i) {
        const int idx = i * 256 + t;
        const int er = idx >> 6, sc = idx & 63;
        dst[(i64)(e0 + er) * S + s0 + sc] = f2bf(tile[sc][er]);
    }
}

__device__ __forceinline__ void cvt_dev(const float4* in, ushort4* outp,
                                        float alpha, i64 i)
{
    const float4 v = in[i];
    ushort4 o;
    o.x = f2bf(v.x * alpha); o.y = f2bf(v.y * alpha);
    o.z = f2bf(v.z * alpha); o.w = f2bf(v.w * alpha);
    outp[i] = o;
}

// =============== prep: converts + transposes + zero Gf (12224 blocks) ===============
__global__ __launch_bounds__(256)
void prep(const float* __restrict__ q, const float* __restrict__ k,
          const float* __restrict__ v,
          const float* __restrict__ Wq, const float* __restrict__ bq,
          const float* __restrict__ Wk, const float* __restrict__ bk,
          const float* __restrict__ Wv, const float* __restrict__ bv,
          const float* __restrict__ Wo, char* __restrict__ ws)
{
    const int b = blockIdx.x, t = threadIdx.x;
    if (b < 4096) {                       // q -> bf16
        cvt_dev((const float4*)q, (ushort4*)(ws + OFF_QB), 1.0f,
                (i64)b * 256 + t);
    } else if (b < 6144) {                // Wo -> bf16
        cvt_dev((const float4*)Wo, (ushort4*)(ws + OFF_WOB), 1.0f,
                (i64)(b - 4096) * 256 + t);
    } else if (b < 7424) {                // k -> kT (aug=1)
        const int l = b - 6144, bz = l / 320, r = l % 320;
        transpose_dev(k + (i64)bz * SQ * EB, nullptr,
                      (u16*)(ws + OFF_KT) + (i64)bz * EP * SQ, SQ, r % 32, r / 32);
    } else if (b < 8704) {                // v -> vT (aug=1)
        const int l = b - 7424, bz = l / 320, r = l % 320;
        transpose_dev(v + (i64)bz * SQ * EB, nullptr,
                      (u16*)(ws + OFF_VT) + (i64)bz * EP * SQ, SQ, r % 32, r / 32);
    } else if (b < 9344) {                // Wq -> WqT (aug=bq)
        const int l = b - 8704, bz = l / 80, r = l % 80;
        transpose_dev(Wq + (i64)bz * EB * EB, bq + (i64)bz * EB,
                      (u16*)(ws + OFF_WQT) + (i64)bz * EP * EB, EB, r % 8, r / 8);
    } else if (b < 9984) {                // Wk -> WkT (aug=bk)
        const int l = b - 9344, bz = l / 80, r = l % 80;
        transpose_dev(Wk + (i64)bz * EB * EB, bk + (i64)bz * EB,
                      (u16*)(ws + OFF_WKT) + (i64)bz * EP * EB, EB, r % 8, r / 8);
    } else if (b < 10624) {               // Wv -> WvT (aug=bv)
        const int l = b - 9984, bz = l / 80, r = l % 80;
        transpose_dev(Wv + (i64)bz * EB * EB, bv + (i64)bz * EB,
                      (u16*)(ws + OFF_WVT) + (i64)bz * EP * EB, EB, r % 8, r / 8);
    } else {                              // zero Gf
        const i64 i = (i64)(b - 10624) * 256 + t;
        ((float4*)(ws + OFF_GF))[i] = (float4){0.f, 0.f, 0.f, 0.f};
    }
}

// =============== cvt1: Gb = bf16(Gf) + zero CTf (2880 blocks) ===============
__global__ __launch_bounds__(256)
void cvt1(char* __restrict__ ws)
{
    const int b = blockIdx.x, t = threadIdx.x;
    if (b < 1600) {
        cvt_dev((const float4*)(ws + OFF_GF), (ushort4*)(ws + OFF_GB), 1.0f,
                (i64)b * 256 + t);
    } else {
        const i64 i = (i64)(b - 1600) * 256 + t;
        ((float4*)(ws + OFF_CTF))[i] = (float4){0.f, 0.f, 0.f, 0.f};
    }
}

// =============== cvt2: CTb = bf16(CTf/512) (1280 blocks) ===============
__global__ __launch_bounds__(256)
void cvt2(char* __restrict__ ws)
{
    cvt_dev((const float4*)(ws + OFF_CTF), (ushort4*)(ws + OFF_CTB),
            1.0f / 512.0f, (i64)blockIdx.x * 256 + threadIdx.x);
}

extern "C" void kernel_launch(void* const* d_in, const int* in_sizes, int n_in,
                              void* d_out, int out_size, void* d_ws, size_t ws_size,
                              hipStream_t stream)
{
    const float* q  = (const float*)d_in[0];
    const float* k  = (const float*)d_in[1];
    const float* v  = (const float*)d_in[2];
    const float* Wq = (const float*)d_in[3];
    const float* bq = (const float*)d_in[4];
    const float* Wk = (const float*)d_in[5];
    const float* bk = (const float*)d_in[6];
    const float* Wv = (const float*)d_in[7];
    const float* bv = (const float*)d_in[8];
    const float* Wo = (const float*)d_in[9];
    const float* bo = (const float*)d_in[10];
    float* out = (float*)d_out;
    char* ws = (char*)d_ws;
    (void)in_sizes; (void)n_in; (void)out_size; (void)ws_size;

    const dim3 blk(256);

    prep<<<dim3(12224), blk, 0, stream>>>(q, k, v, Wq, bq, Wk, bk, Wv, bv, Wo, ws);
    gemm_stage1<<<dim3(760), blk, 0, stream>>>(ws);
    cvt1<<<dim3(2880), blk, 0, stream>>>(ws);
    gemm_zg<<<dim3(4, 5, NB * NH), blk, 0, stream>>>(ws);
    gemm_ct<<<dim3(4, 5, NB * 8), blk, 0, stream>>>(ws);
    cvt2<<<dim3(1280), blk, 0, stream>>>(ws);
    gemm_out<<<dim3(16, 4, NB), blk, 0, stream>>>(ws, out, bo);
}

// Round 4
// 279.897 us; speedup vs baseline: 5.6656x; 1.0275x over previous
//
#include <hip/hip_runtime.h>

// B=4,S=2048,E=512,H=8. Linear attention (no softmax) collapsed to GEMM chain:
//  out[b] = q~[b]*C~[b]+bo,  C~[b]=(1/512) sum_h U~[h] G~[b] Z~[h]^T
// Reordered: ZG[b,h]=Z~[h]*G~[b]^T, CT[b]=ZGcat[b]*Ucat^T (K=5120). ~44 GF bf16.
// All GEMMs: NT 128x128 tile, BK=64, 2-phase double-buffered global_load_lds(16B),
// pre-swizzled source + XOR-swizzled ds_read_b128, 16x16x32 bf16 MFMA, fp32 acc.
// NO atomics: CT split-K writes fragment-layout f32x4 partials, reduced by cvt2.

typedef long long i64;
typedef unsigned short u16;
typedef __attribute__((ext_vector_type(8))) short bf16x8;
typedef __attribute__((ext_vector_type(4))) float f32x4;

#define EB 512
#define EP 640
#define SQ 2048
#define NB 4
#define NH 8
#define HEP 5120

// ---- workspace byte offsets (peak 70,909,952) ----
#define OFF_QB    0ll          //  8,388,608  bf16 q [4][2048][512]      (prep->out)
#define OFF_KT    8388608ll    // 10,485,760  bf16 kT [4][640][2048]     (prep->stage1)
#define OFF_VT    18874368ll   // 10,485,760  bf16 vT                    (prep->stage1)
#define OFF_WQT   29360128ll   //  5,242,880  bf16 WqT [8][640][512]     (prep->stage1)
#define OFF_WKT   34603008ll   //  5,242,880                             (prep->stage1)
#define OFF_WVT   39845888ll   //  5,242,880                             (prep->stage1)
#define OFF_WOB   45088768ll   //  4,194,304  bf16 Wo [512][4096]        (prep->stage1)
#define OFF_ZCAT  49283072ll   //  5,242,880  bf16 Zcat [512][5120]      (stage1->zg)
#define OFF_UCAT  61079552ll   //  6,553,600  bf16 Ucat [640][5120]      (stage1->ct)
#define OFF_GB    67633152ll   //  3,276,800  bf16 Gb [4][640][640]      (stage1->zg)
#define OFF_ZGC   8388608ll    // 20,971,520  bf16 ZGcat [4][512][5120]  (zg->ct, alias KT+VT)
#define OFF_CTP   29360128ll   // 20,971,520  f32 CT partials [4][4][20][16384] (ct->cvt2, alias W*,ZCAT-head)
#define OFF_CTB   50331648ll   //  2,621,440  bf16 CTb [4][512][640]     (cvt2->out, alias ZCAT-tail)
#define OFF_RB    52953088ll   //      8,192  f32 rb [4][512]            (cvt2->out)

__device__ __forceinline__ u16 f2bf(float x) {
    unsigned u = __float_as_uint(x);
    return (u16)((u + 0x7fffu + ((u >> 16) & 1u)) >> 16);
}

__device__ __forceinline__ void gload16(const void* g, void* l) {
    __builtin_amdgcn_global_load_lds(
        (const __attribute__((address_space(1))) unsigned int*)g,
        (__attribute__((address_space(3))) unsigned int*)l, 16, 0, 0);
}

// bijective XCD swizzle (m204): consecutive returned ids stay on one XCD chunk
__device__ __forceinline__ int xcd_swz(int b, int n) {
    const int x = b & 7, o = b >> 3, q = n >> 3, r = n & 7;
    return (x < r ? x * (q + 1) : r * (q + 1) + (x - r) * q) + o;
}

// =============== shared GEMM body: C = A * B^T, 128x128 tile, BK=64 ===============
// epi 0: bf16 store. epi 2: f32 store + rb[col]+bo[col]. epi 3: fragment-layout
// f32x4 partial store (Cv = per-(split,tile) 64KB block).
__device__ __forceinline__ void gemm_body(
    const u16* __restrict__ A, i64 lda, const u16* __restrict__ B, i64 ldb,
    int bx, int by, int K, int epi, void* Cv, i64 ldc,
    const float* rbias, const float* bo,
    char* lA0, char* lA1, char* lB0, char* lB1)
{
    const i64 m0 = (i64)bx * 128, n0 = (i64)by * 128;
    const int tid = threadIdx.x, lane = tid & 63, wid = tid >> 6;
    const int wr = wid >> 1, wc = wid & 1;
    const int g = lane >> 4, li = lane & 15;

    i64 offA[4], offB[4]; int lofs[4];
#pragma unroll
    for (int i = 0; i < 4; ++i) {
        const int chunk = i * 4 + wid;
        const int rr = chunk * 8 + (lane >> 3);
        const int gc = ((lane & 7) ^ (rr & 7)) << 3;   // pre-swizzled col chunk
        offA[i] = (m0 + rr) * lda + gc;
        offB[i] = (n0 + rr) * ldb + gc;
        lofs[i] = chunk * 1024;
    }
    const int ldest = lane * 16;

    f32x4 acc[4][4];
#pragma unroll
    for (int a_ = 0; a_ < 4; ++a_)
#pragma unroll
        for (int b_ = 0; b_ < 4; ++b_) acc[a_][b_] = (f32x4){0.f, 0.f, 0.f, 0.f};

    char* bufA[2] = {lA0, lA1};
    char* bufB[2] = {lB0, lB1};
    const int nIt = K >> 6;

#pragma unroll
    for (int i = 0; i < 4; ++i) {
        gload16(A + offA[i], bufA[0] + lofs[i] + ldest);
        gload16(B + offB[i], bufB[0] + lofs[i] + ldest);
    }
    __syncthreads();

    int cur = 0;
    for (int it = 0; it < nIt; ++it) {
        if (it + 1 < nIt) {
            const i64 k0 = (i64)(it + 1) << 6;
#pragma unroll
            for (int i = 0; i < 4; ++i) {
                gload16(A + offA[i] + k0, bufA[cur ^ 1] + lofs[i] + ldest);
                gload16(B + offB[i] + k0, bufB[cur ^ 1] + lofs[i] + ldest);
            }
        }
        char* cA = bufA[cur];
        char* cB = bufB[cur];
#pragma unroll
        for (int ks = 0; ks < 2; ++ks) {
            bf16x8 af[4], bfr[4];
#pragma unroll
            for (int f = 0; f < 4; ++f) {
                const int row = wr * 64 + f * 16 + li;
                const int slot = (ks * 4 + g) ^ (row & 7);
                af[f] = *(const bf16x8*)(cA + row * 128 + slot * 16);
            }
#pragma unroll
            for (int f = 0; f < 4; ++f) {
                const int row = wc * 64 + f * 16 + li;
                const int slot = (ks * 4 + g) ^ (row & 7);
                bfr[f] = *(const bf16x8*)(cB + row * 128 + slot * 16);
            }
#pragma unroll
            for (int fm = 0; fm < 4; ++fm)
#pragma unroll
                for (int fn = 0; fn < 4; ++fn)
                    acc[fm][fn] = __builtin_amdgcn_mfma_f32_16x16x32_bf16(
                        af[fm], bfr[fn], acc[fm][fn], 0, 0, 0);
        }
        __syncthreads();
        cur ^= 1;
    }

    if (epi == 0) {
        u16* C = (u16*)Cv;
#pragma unroll
        for (int fm = 0; fm < 4; ++fm)
#pragma unroll
            for (int fn = 0; fn < 4; ++fn) {
                const i64 col = n0 + wc * 64 + fn * 16 + li;
#pragma unroll
                for (int q = 0; q < 4; ++q) {
                    const i64 row = m0 + wr * 64 + fm * 16 + g * 4 + q;
                    C[row * ldc + col] = f2bf(acc[fm][fn][q]);
                }
            }
    } else if (epi == 2) {
        float* C = (float*)Cv;
#pragma unroll
        for (int fn = 0; fn < 4; ++fn) {
            const i64 col = n0 + wc * 64 + fn * 16 + li;
            const float bb = rbias[col] + bo[col];
#pragma unroll
            for (int fm = 0; fm < 4; ++fm)
#pragma unroll
                for (int q = 0; q < 4; ++q) {
                    const i64 row = m0 + wr * 64 + fm * 16 + g * 4 + q;
                    C[row * ldc + col] = acc[fm][fn][q] + bb;
                }
        }
    } else {   // epi 3: fragment-layout partial, fully coalesced f32x4
        float* C = (float*)Cv;
#pragma unroll
        for (int fm = 0; fm < 4; ++fm)
#pragma unroll
            for (int fn = 0; fn < 4; ++fn)
                *(f32x4*)(C + (fm * 4 + fn) * 1024 + tid * 4) = acc[fm][fn];
    }
}

#define GEMM_LDS \
    __shared__ __align__(16) char lA0[16384], lA1[16384]; \
    __shared__ __align__(16) char lB0[16384], lB1[16384];

// ===== stage 1 fused: U (200 blk, K=512) + Z (160 blk, K=512) + G (100 blk, K=2048)
__global__ __launch_bounds__(256)
void gemm_stage1(char* __restrict__ ws)
{
    GEMM_LDS
    const int b = xcd_swz(blockIdx.x, 460);
    const u16* A; const u16* B; i64 lda, ldb, ldc; void* C;
    int bx, by, K;
    if (b < 200) {            // U[h] = W~q^T W~k -> Ucat[640][5120] col h*640
        const int h = b / 25, r = b % 25;
        bx = r / 5; by = r % 5;
        A = (const u16*)(ws + OFF_WQT) + (i64)h * EP * EB; lda = EB;
        B = (const u16*)(ws + OFF_WKT) + (i64)h * EP * EB; ldb = EB;
        C = (u16*)(ws + OFF_UCAT) + (i64)h * EP; ldc = HEP;
        K = EB;
    } else if (b < 360) {     // Z[h] = Wo_h W~v -> Zcat[512][5120] col h*640
        const int t = b - 200, h = t / 20, r = t % 20;
        bx = r / 5; by = r % 5;
        A = (const u16*)(ws + OFF_WOB) + (i64)h * EB; lda = (i64)NH * EB;
        B = (const u16*)(ws + OFF_WVT) + (i64)h * EP * EB; ldb = EB;
        C = (u16*)(ws + OFF_ZCAT) + (i64)h * EP; ldc = HEP;
        K = EB;
    } else {                  // G[b] = k~^T v~ -> bf16 Gb[b][640][640], K=2048
        const int t = b - 360, bb = t / 25, r = t % 25;
        bx = r / 5; by = r % 5;
        A = (const u16*)(ws + OFF_KT) + (i64)bb * EP * SQ; lda = SQ;
        B = (const u16*)(ws + OFF_VT) + (i64)bb * EP * SQ; ldb = SQ;
        C = (u16*)(ws + OFF_GB) + (i64)bb * EP * EP; ldc = EP;
        K = SQ;
    }
    gemm_body(A, lda, B, ldb, bx, by, K, 0, C, ldc, nullptr, nullptr,
              lA0, lA1, lB0, lB1);
}

// ===== stage 2: ZG[b,h] = Z[h] * G[b]^T -> ZGcat[b][512][5120]  (640 blocks)
__global__ __launch_bounds__(256)
void gemm_zg(char* __restrict__ ws)
{
    GEMM_LDS
    const int id = xcd_swz(blockIdx.x, 640);
    const int z = id / 20, t = id % 20, bb = z >> 3, h = z & 7;
    const int bx = t / 5, by = t % 5;
    const u16* A = (const u16*)(ws + OFF_ZCAT) + (i64)h * EP;
    const u16* B = (const u16*)(ws + OFF_GB) + (i64)bb * EP * EP;
    u16* C = (u16*)(ws + OFF_ZGC) + (i64)bb * EB * HEP + (i64)h * EP;
    gemm_body(A, HEP, B, EP, bx, by, EP, 0, C, HEP,
              nullptr, nullptr, lA0, lA1, lB0, lB1);
}

// ===== stage 3: CT partials = ZGcat[b] * Ucat^T, K=5120 split 4x1280 (320 blocks)
__global__ __launch_bounds__(256)
void gemm_ct(char* __restrict__ ws)
{
    GEMM_LDS
    const int id = xcd_swz(blockIdx.x, 320);
    const int z = id / 20, t = id % 20, bb = z >> 2, sp = z & 3;
    const int bx = t / 5, by = t % 5;
    const u16* A = (const u16*)(ws + OFF_ZGC) + (i64)bb * EB * HEP + (i64)sp * 1280;
    const u16* B = (const u16*)(ws + OFF_UCAT) + (i64)sp * 1280;
    float* C = (float*)(ws + OFF_CTP) + ((i64)(bb * 4 + sp) * 20 + t) * 16384;
    gemm_body(A, HEP, B, HEP, bx, by, 1280, 3, C, 0,
              nullptr, nullptr, lA0, lA1, lB0, lB1);
}

// ===== cvt2: reduce 4 CT partials -> CTb bf16 (/512) + rb f32 row  (80 blocks)
__global__ __launch_bounds__(256)
void cvt2(char* __restrict__ ws)
{
    const int gblk = blockIdx.x;
    const int b = gblk / 20, t = gblk % 20;
    const int bx = t / 5, by = t % 5;
    const int tid = threadIdx.x, lane = tid & 63, wid = tid >> 6;
    const int wr = wid >> 1, wc = wid & 1, g = lane >> 4, li = lane & 15;
    const float* base = (const float*)(ws + OFF_CTP) + ((i64)b * 4 * 20 + t) * 16384;
    u16* ctb = (u16*)(ws + OFF_CTB) + (i64)b * EB * EP;
    float* rb = (float*)(ws + OFF_RB) + (i64)b * EB;
#pragma unroll
    for (int fm = 0; fm < 4; ++fm)
#pragma unroll
        for (int fn = 0; fn < 4; ++fn) {
            const int fo = (fm * 4 + fn) * 1024 + tid * 4;
            f32x4 s = *(const f32x4*)(base + fo);
#pragma unroll
            for (int p = 1; p < 4; ++p) {
                f32x4 u = *(const f32x4*)(base + (i64)p * 20 * 16384 + fo);
                s[0] += u[0]; s[1] += u[1]; s[2] += u[2]; s[3] += u[3];
            }
            const int row0 = bx * 128 + wr * 64 + fm * 16 + g * 4;
            const int col = by * 128 + wc * 64 + fn * 16 + li;
#pragma unroll
            for (int q = 0; q < 4; ++q) {
                const float val = s[q] * (1.0f / 512.0f);
                ctb[(i64)(row0 + q) * EP + col] = f2bf(val);
                if (col == 512) rb[row0 + q] = val;
            }
        }
}

// ===== stage 4: out[b] = qb[b]*CTb[b]^T + rb + bo  (256 blocks)
__global__ __launch_bounds__(256)
void gemm_out(char* __restrict__ ws, float* __restrict__ out,
              const float* __restrict__ bo)
{
    GEMM_LDS
    const int id = xcd_swz(blockIdx.x, 256);
    const int bb = id / 64, t = id % 64;
    const int bx = t / 4, by = t % 4;
    const u16* A = (const u16*)(ws + OFF_QB) + (i64)bb * SQ * EB;
    const u16* B = (const u16*)(ws + OFF_CTB) + (i64)bb * EB * EP;
    float* C = out + (i64)bb * SQ * EB;
    const float* rb = (const float*)(ws + OFF_RB) + (i64)bb * EB;
    gemm_body(A, EB, B, EP, bx, by, EB, 2, C, EB,
              rb, bo, lA0, lA1, lB0, lB1);
}

// =============== transpose+aug: f32 [Sx512] -> bf16 [640xS] ===============
__device__ __forceinline__ void transpose_dev(
    const float* __restrict__ src, const float* __restrict__ aug,
    u16* __restrict__ dst, int S, int bx, int by)
{
    const int s0 = bx * 64, e0 = by * 64;
    const int t = threadIdx.x;
    if (e0 >= EB) {
#pragma unroll
        for (int i = 0; i < 16; ++i) {
            const int idx = i * 256 + t;
            const int er = idx >> 6, sc = idx & 63;
            const int e = e0 + er;
            u16 val = 0;
            if (e == EB) val = f2bf(aug ? aug[s0 + sc] : 1.0f);
            dst[(i64)e * S + s0 + sc] = val;
        }
        return;
    }
    __shared__ float tile[64][65];
#pragma unroll
    for (int i = 0; i < 16; ++i) {
        const int idx = i * 256 + t;
        const int sr = idx >> 6, ec = idx & 63;
        tile[sr][ec] = src[(i64)(s0 + sr) * EB + e0 + ec];
    }
    __syncthreads();
#pragma unroll
    for (int i = 0; i < 16; ++i) {
        const int idx = i * 256 + t;
        const int er = idx >> 6, sc = idx & 63;
        dst[(i64)(e0 + er) * S + s0 + sc] = f2bf(tile[sc][er]);
    }
}

__device__ __forceinline__ void cvt_dev(const float4* in, ushort4* outp,
                                        float alpha, i64 i)
{
    const float4 v = in[i];
    ushort4 o;
    o.x = f2bf(v.x * alpha); o.y = f2bf(v.y * alpha);
    o.z = f2bf(v.z * alpha); o.w = f2bf(v.w * alpha);
    outp[i] = o;
}

// ===== prep: converts + transposes (10624 blocks)
__global__ __launch_bounds__(256)
void prep(const float* __restrict__ q, const float* __restrict__ k,
          const float* __restrict__ v,
          const float* __restrict__ Wq, const float* __restrict__ bq,
          const float* __restrict__ Wk, const float* __restrict__ bk,
          const float* __restrict__ Wv, const float* __restrict__ bv,
          const float* __restrict__ Wo, char* __restrict__ ws)
{
    const int b = blockIdx.x, t = threadIdx.x;
    if (b < 4096) {
        cvt_dev((const float4*)q, (ushort4*)(ws + OFF_QB), 1.0f, (i64)b * 256 + t);
    } else if (b < 6144) {
        cvt_dev((const float4*)Wo, (ushort4*)(ws + OFF_WOB), 1.0f,
                (i64)(b - 4096) * 256 + t);
    } else if (b < 7424) {
        const int l = b - 6144, bz = l / 320, r = l % 320;
        transpose_dev(k + (i64)bz * SQ * EB, nullptr,
                      (u16*)(ws + OFF_KT) + (i64)bz * EP * SQ, SQ, r % 32, r / 32);
    } else if (b < 8704) {
        const int l = b - 7424, bz = l / 320, r = l % 320;
        transpose_dev(v + (i64)bz * SQ * EB, nullptr,
                      (u16*)(ws + OFF_VT) + (i64)bz * EP * SQ, SQ, r % 32, r / 32);
    } else if (b < 9344) {
        const int l = b - 8704, bz = l / 80, r = l % 80;
        transpose_dev(Wq + (i64)bz * EB * EB, bq + (i64)bz * EB,
                      (u16*)(ws + OFF_WQT) + (i64)bz * EP * EB, EB, r % 8, r / 8);
    } else if (b < 9984) {
        const int l = b - 9344, bz = l / 80, r = l % 80;
        transpose_dev(Wk + (i64)bz * EB * EB, bk + (i64)bz * EB,
                      (u16*)(ws + OFF_WKT) + (i64)bz * EP * EB, EB, r % 8, r / 8);
    } else {
        const int l = b - 9984, bz = l / 80, r = l % 80;
        transpose_dev(Wv + (i64)bz * EB * EB, bv + (i64)bz * EB,
                      (u16*)(ws + OFF_WVT) + (i64)bz * EP * EB, EB, r % 8, r / 8);
    }
}

extern "C" void kernel_launch(void* const* d_in, const int* in_sizes, int n_in,
                              void* d_out, int out_size, void* d_ws, size_t ws_size,
                              hipStream_t stream)
{
    const float* q  = (const float*)d_in[0];
    const float* k  = (const float*)d_in[1];
    const float* v  = (const float*)d_in[2];
    const float* Wq = (const float*)d_in[3];
    const float* bq = (const float*)d_in[4];
    const float* Wk = (const float*)d_in[5];
    const float* bk = (const float*)d_in[6];
    const float* Wv = (const float*)d_in[7];
    const float* bv = (const float*)d_in[8];
    const float* Wo = (const float*)d_in[9];
    const float* bo = (const float*)d_in[10];
    float* out = (float*)d_out;
    char* ws = (char*)d_ws;
    (void)in_sizes; (void)n_in; (void)out_size; (void)ws_size;

    const dim3 blk(256);

    prep<<<dim3(10624), blk, 0, stream>>>(q, k, v, Wq, bq, Wk, bk, Wv, bv, Wo, ws);
    gemm_stage1<<<dim3(460), blk, 0, stream>>>(ws);
    gemm_zg<<<dim3(640), blk, 0, stream>>>(ws);
    gemm_ct<<<dim3(320), blk, 0, stream>>>(ws);
    cvt2<<<dim3(80), blk, 0, stream>>>(ws);
    gemm_out<<<dim3(256), blk, 0, stream>>>(ws, out, bo);
}

// Round 7
// 264.189 us; speedup vs baseline: 6.0025x; 1.0595x over previous
//
#include <hip/hip_runtime.h>

// B=4,S=2048,E=512,H=8. Linear attention (no softmax) collapsed to GEMM chain:
//  out[b] = q~[b]*C~[b]+bo,  C~[b]=(1/512) sum_h U~[h] G~[b] Z~[h]^T
// Multi-launch (7 kernels), balanced unit decomposition, no atomics anywhere.
//  L0 prep (transposes/converts)            4992 blocks
//  L1 stage1: U+Z (8it) + G splitK2 (16it)   560 blocks, G dispatched first
//  L2 gred: G partials -> bf16 Gb            100 blocks
//  L3 zg: ZG[b,h]=Z[h]G[b]^T                 640 blocks
//  L4 ct: CT partials = ZG*Ucat^T splitK4    320 blocks
//  L5 cvt2: CT reduce + q->bf16             1104 blocks
//  L6 out = q~ * CT^T + biases               256 blocks
// GEMM: NT 128x128 tile, BK=64, 2-phase dbuf global_load_lds(16B),
// pre-swizzled source + XOR-swizzled ds_read_b128, 16x16x32 bf16 MFMA, f32 acc.

typedef long long i64;
typedef unsigned short u16;
typedef __attribute__((ext_vector_type(8))) short bf16x8;
typedef __attribute__((ext_vector_type(4))) float f32x4;

#define EB 512
#define EP 640
#define SQ 2048
#define NB 4
#define NH 8
#define HEP 5120

// ---- workspace byte offsets (peak 69,074,944) ----
#define OFF_KT    0ll          // 10,485,760  bf16 kT [4][640][2048]   L0->L1
#define OFF_VT    10485760ll   // 10,485,760  bf16 vT                  L0->L1
#define OFF_WQT   20971520ll   //  5,242,880  bf16 WqT [8][640][512]   L0->L1
#define OFF_WKT   26214400ll   //  5,242,880                           L0->L1
#define OFF_WVT   31457280ll   //  5,242,880                           L0->L1
#define OFF_WOB   36700160ll   //  4,194,304  bf16 Wo [512][4096]      L0->L1
#define OFF_ZCAT  40894464ll   //  5,242,880  bf16 Zcat [512][5120]    L1->L3
#define OFF_UCAT  46137344ll   //  6,553,600  bf16 Ucat [640][5120]    L1->L4
#define OFF_GP    52690944ll   // 13,107,200  f32 G partials [4][2][25][16384] L1->L2
#define OFF_GB    65798144ll   //  3,276,800  bf16 Gb [4][640][640]    L2->L3
#define OFF_ZGC   0ll          // 20,971,520  bf16 ZGcat [4][512][5120] L3->L4 (alias KT+VT)
#define OFF_CTP   20971520ll   // 20,971,520  f32 CT partials [4][4][20][16384] L4->L5 (alias W*,ZCAT)
#define OFF_QB    0ll          //  8,388,608  bf16 q [4][2048][512]    L5->L6 (alias ZGC)
#define OFF_CTB   46137344ll   //  2,621,440  bf16 CTb [4][512][640]   L5->L6 (alias UCAT)
#define OFF_RB    48758784ll   //      8,192  f32 rb [4][512]          L5->L6

__device__ __forceinline__ u16 f2bf(float x) {
    unsigned u = __float_as_uint(x);
    return (u16)((u + 0x7fffu + ((u >> 16) & 1u)) >> 16);
}

__device__ __forceinline__ void gload16(const void* g, void* l) {
    __builtin_amdgcn_global_load_lds(
        (const __attribute__((address_space(1))) unsigned int*)g,
        (__attribute__((address_space(3))) unsigned int*)l, 16, 0, 0);
}

// =============== GEMM body: C = A * B^T, 128x128 tile, BK=64 ===============
// epi 0: bf16 store. epi 2: f32 store + rb[col]+bo[col]. epi 3: fragment-layout
// f32x4 partial store (Cv = 64KB tile block; ldc/m0/n0 unused).
__device__ __forceinline__ void gemm_body(
    const u16* __restrict__ A, i64 lda, const u16* __restrict__ B, i64 ldb,
    int bx, int by, int K, int epi, void* Cv, i64 ldc,
    const float* rbias, const float* bo, char* pool)
{
    char* lA0 = pool;
    char* lA1 = pool + 16384;
    char* lB0 = pool + 32768;
    char* lB1 = pool + 49152;
    const i64 m0 = (i64)bx * 128, n0 = (i64)by * 128;
    const int tid = threadIdx.x, lane = tid & 63, wid = tid >> 6;
    const int wr = wid >> 1, wc = wid & 1;
    const int g = lane >> 4, li = lane & 15;

    i64 offA[4], offB[4]; int lofs[4];
#pragma unroll
    for (int i = 0; i < 4; ++i) {
        const int chunk = i * 4 + wid;
        const int rr = chunk * 8 + (lane >> 3);
        const int gc = ((lane & 7) ^ (rr & 7)) << 3;   // pre-swizzled col chunk
        offA[i] = (m0 + rr) * lda + gc;
        offB[i] = (n0 + rr) * ldb + gc;
        lofs[i] = chunk * 1024;
    }
    const int ldest = lane * 16;

    f32x4 acc[4][4];
#pragma unroll
    for (int a_ = 0; a_ < 4; ++a_)
#pragma unroll
        for (int b_ = 0; b_ < 4; ++b_) acc[a_][b_] = (f32x4){0.f, 0.f, 0.f, 0.f};

    char* bufA[2] = {lA0, lA1};
    char* bufB[2] = {lB0, lB1};
    const int nIt = K >> 6;

#pragma unroll
    for (int i = 0; i < 4; ++i) {
        gload16(A + offA[i], bufA[0] + lofs[i] + ldest);
        gload16(B + offB[i], bufB[0] + lofs[i] + ldest);
    }
    __syncthreads();

    int cur = 0;
    for (int it = 0; it < nIt; ++it) {
        if (it + 1 < nIt) {
            const i64 k0 = (i64)(it + 1) << 6;
#pragma unroll
            for (int i = 0; i < 4; ++i) {
                gload16(A + offA[i] + k0, bufA[cur ^ 1] + lofs[i] + ldest);
                gload16(B + offB[i] + k0, bufB[cur ^ 1] + lofs[i] + ldest);
            }
        }
        char* cA = bufA[cur];
        char* cB = bufB[cur];
#pragma unroll
        for (int ks = 0; ks < 2; ++ks) {
            bf16x8 af[4], bfr[4];
#pragma unroll
            for (int f = 0; f < 4; ++f) {
                const int row = wr * 64 + f * 16 + li;
                const int slot = (ks * 4 + g) ^ (row & 7);
                af[f] = *(const bf16x8*)(cA + row * 128 + slot * 16);
            }
#pragma unroll
            for (int f = 0; f < 4; ++f) {
                const int row = wc * 64 + f * 16 + li;
                const int slot = (ks * 4 + g) ^ (row & 7);
                bfr[f] = *(const bf16x8*)(cB + row * 128 + slot * 16);
            }
#pragma unroll
            for (int fm = 0; fm < 4; ++fm)
#pragma unroll
                for (int fn = 0; fn < 4; ++fn)
                    acc[fm][fn] = __builtin_amdgcn_mfma_f32_16x16x32_bf16(
                        af[fm], bfr[fn], acc[fm][fn], 0, 0, 0);
        }
        __syncthreads();
        cur ^= 1;
    }

    if (epi == 0) {
        u16* C = (u16*)Cv;
#pragma unroll
        for (int fm = 0; fm < 4; ++fm)
#pragma unroll
            for (int fn = 0; fn < 4; ++fn) {
                const i64 col = n0 + wc * 64 + fn * 16 + li;
#pragma unroll
                for (int q = 0; q < 4; ++q) {
                    const i64 row = m0 + wr * 64 + fm * 16 + g * 4 + q;
                    C[row * ldc + col] = f2bf(acc[fm][fn][q]);
                }
            }
    } else if (epi == 2) {
        float* C = (float*)Cv;
#pragma unroll
        for (int fn = 0; fn < 4; ++fn) {
            const i64 col = n0 + wc * 64 + fn * 16 + li;
            const float bb = rbias[col] + bo[col];
#pragma unroll
            for (int fm = 0; fm < 4; ++fm)
#pragma unroll
                for (int q = 0; q < 4; ++q) {
                    const i64 row = m0 + wr * 64 + fm * 16 + g * 4 + q;
                    C[row * ldc + col] = acc[fm][fn][q] + bb;
                }
        }
    } else {   // epi 3: fragment-layout partial, fully coalesced f32x4
        float* C = (float*)Cv;
#pragma unroll
        for (int fm = 0; fm < 4; ++fm)
#pragma unroll
            for (int fn = 0; fn < 4; ++fn)
                *(f32x4*)(C + (fm * 4 + fn) * 1024 + tid * 4) = acc[fm][fn];
    }
}

#define GEMM_LDS __shared__ __align__(16) char pool[65536];

// =============== transpose+aug: f32 [Sx512] -> bf16 [640xS] ===============
__device__ __forceinline__ void transpose_dev(
    const float* __restrict__ src, const float* __restrict__ aug,
    u16* __restrict__ dst, int S, int bx, int by, char* pool)
{
    const int s0 = bx * 64, e0 = by * 64;
    const int t = threadIdx.x;
    if (e0 >= EB) {
#pragma unroll
        for (int i = 0; i < 16; ++i) {
            const int idx = i * 256 + t;
            const int er = idx >> 6, sc = idx & 63;
            const int e = e0 + er;
            u16 val = 0;
            if (e == EB) val = f2bf(aug ? aug[s0 + sc] : 1.0f);
            dst[(i64)e * S + s0 + sc] = val;
        }
        return;
    }
    float (*tile)[65] = (float(*)[65])pool;
#pragma unroll
    for (int i = 0; i < 16; ++i) {
        const int idx = i * 256 + t;
        const int sr = idx >> 6, ec = idx & 63;
        tile[sr][ec] = src[(i64)(s0 + sr) * EB + e0 + ec];
    }
    __syncthreads();
#pragma unroll
    for (int i = 0; i < 16; ++i) {
        const int idx = i * 256 + t;
        const int er = idx >> 6, sc = idx & 63;
        dst[(i64)(e0 + er) * S + s0 + sc] = f2bf(tile[sc][er]);
    }
}

__device__ __forceinline__ void cvt_dev(const float4* in, ushort4* outp,
                                        float alpha, i64 i)
{
    const float4 v = in[i];
    ushort4 o;
    o.x = f2bf(v.x * alpha); o.y = f2bf(v.y * alpha);
    o.z = f2bf(v.z * alpha); o.w = f2bf(v.w * alpha);
    outp[i] = o;
}

// ===== L0 prep: transposes + Wo convert (4992 blocks)
__global__ __launch_bounds__(256)
void prep(const float* __restrict__ k, const float* __restrict__ v,
          const float* __restrict__ Wq, const float* __restrict__ bq,
          const float* __restrict__ Wk, const float* __restrict__ bk,
          const float* __restrict__ Wv, const float* __restrict__ bv,
          const float* __restrict__ Wo, char* __restrict__ ws)
{
    __shared__ __align__(16) char pool[16640];
    const int u = blockIdx.x, t = threadIdx.x;
    if (u < 1280) {               // kT
        const int bz = u / 320, r = u % 320;
        transpose_dev(k + (i64)bz * SQ * EB, nullptr,
                      (u16*)(ws + OFF_KT) + (i64)bz * EP * SQ, SQ,
                      r % 32, r / 32, pool);
    } else if (u < 2560) {        // vT
        const int l = u - 1280, bz = l / 320, r = l % 320;
        transpose_dev(v + (i64)bz * SQ * EB, nullptr,
                      (u16*)(ws + OFF_VT) + (i64)bz * EP * SQ, SQ,
                      r % 32, r / 32, pool);
    } else if (u < 3200) {        // WqT
        const int l = u - 2560, bz = l / 80, r = l % 80;
        transpose_dev(Wq + (i64)bz * EB * EB, bq + (i64)bz * EB,
                      (u16*)(ws + OFF_WQT) + (i64)bz * EP * EB, EB,
                      r % 8, r / 8, pool);
    } else if (u < 3840) {        // WkT
        const int l = u - 3200, bz = l / 80, r = l % 80;
        transpose_dev(Wk + (i64)bz * EB * EB, bk + (i64)bz * EB,
                      (u16*)(ws + OFF_WKT) + (i64)bz * EP * EB, EB,
                      r % 8, r / 8, pool);
    } else if (u < 4480) {        // WvT
        const int l = u - 3840, bz = l / 80, r = l % 80;
        transpose_dev(Wv + (i64)bz * EB * EB, bv + (i64)bz * EB,
                      (u16*)(ws + OFF_WVT) + (i64)bz * EP * EB, EB,
                      r % 8, r / 8, pool);
    } else {                      // Wo cvt (512 units x 1024 float4)
        const i64 j = u - 4480;
#pragma unroll
        for (int s = 0; s < 4; ++s)
            cvt_dev((const float4*)Wo, (ushort4*)(ws + OFF_WOB), 1.0f,
                    j * 1024 + s * 256 + t);
    }
}

// ===== L1 stage1: G splitK2 (200 units, 16it, dispatched FIRST) + U/Z (360, 8it)
// XCD chunking: x = bid&7, o = bid>>3; o<25 -> G unit x*25+o; else UZ x*45+(o-25).
__global__ __launch_bounds__(256)
void stage1(char* __restrict__ ws)
{
    GEMM_LDS
    const int x = blockIdx.x & 7, o = blockIdx.x >> 3;
    if (o < 25) {                 // G split-K partial (K=1024, epi3 f32 partial)
        const int gu = x * 25 + o;
        const int b = gu / 50, sp = (gu % 50) / 25, r = gu % 25;
        const u16* A = (const u16*)(ws + OFF_KT) + (i64)b * EP * SQ + sp * 1024;
        const u16* B = (const u16*)(ws + OFF_VT) + (i64)b * EP * SQ + sp * 1024;
        float* C = (float*)(ws + OFF_GP) + ((i64)(b * 2 + sp) * 25 + r) * 16384;
        gemm_body(A, SQ, B, SQ, r / 5, r % 5, 1024, 3, C, 0, nullptr, nullptr, pool);
    } else {
        const int j = x * 45 + (o - 25);    // 0..359
        if (j < 200) {            // U[h] -> Ucat col h*640
            const int h = j / 25, r = j % 25;
            gemm_body((const u16*)(ws + OFF_WQT) + (i64)h * EP * EB, EB,
                      (const u16*)(ws + OFF_WKT) + (i64)h * EP * EB, EB,
                      r / 5, r % 5, EB, 0,
                      (u16*)(ws + OFF_UCAT) + (i64)h * EP, HEP,
                      nullptr, nullptr, pool);
        } else {                  // Z[h] -> Zcat col h*640
            const int j2 = j - 200, h = j2 / 20, r = j2 % 20;
            gemm_body((const u16*)(ws + OFF_WOB) + (i64)h * EB, (i64)NH * EB,
                      (const u16*)(ws + OFF_WVT) + (i64)h * EP * EB, EB,
                      r / 5, r % 5, EB, 0,
                      (u16*)(ws + OFF_ZCAT) + (i64)h * EP, HEP,
                      nullptr, nullptr, pool);
        }
    }
}

// ===== L2 gred: reduce 2 G partials -> bf16 Gb (100 blocks)
__global__ __launch_bounds__(256)
void gred(char* __restrict__ ws)
{
    const int u = blockIdx.x;
    const int b = u / 25, t = u % 25;
    const int bx = t / 5, by = t % 5;
    const int tid = threadIdx.x, lane = tid & 63, wid = tid >> 6;
    const int wr = wid >> 1, wc = wid & 1, g = lane >> 4, li = lane & 15;
    const float* base = (const float*)(ws + OFF_GP) + ((i64)b * 2 * 25 + t) * 16384;
    u16* gb = (u16*)(ws + OFF_GB) + (i64)b * EP * EP;
#pragma unroll
    for (int fm = 0; fm < 4; ++fm)
#pragma unroll
        for (int fn = 0; fn < 4; ++fn) {
            const int fo = (fm * 4 + fn) * 1024 + tid * 4;
            f32x4 s = *(const f32x4*)(base + fo);
            f32x4 p1 = *(const f32x4*)(base + 25 * 16384 + fo);
            s[0] += p1[0]; s[1] += p1[1]; s[2] += p1[2]; s[3] += p1[3];
            const int row0 = bx * 128 + wr * 64 + fm * 16 + g * 4;
            const int col = by * 128 + wc * 64 + fn * 16 + li;
#pragma unroll
            for (int qq = 0; qq < 4; ++qq)
                gb[(i64)(row0 + qq) * EP + col] = f2bf(s[qq]);
        }
}

// ===== L3 zg: ZG[b,h] = Z[h] * G[b]^T (640 blocks, K=640)
__global__ __launch_bounds__(256)
void zg(char* __restrict__ ws)
{
    GEMM_LDS
    const int x = blockIdx.x & 7, o = blockIdx.x >> 3;
    const int id = x * 80 + o;
    const int z = id / 20, t = id % 20, b = z >> 3, h = z & 7;
    gemm_body((const u16*)(ws + OFF_ZCAT) + (i64)h * EP, HEP,
              (const u16*)(ws + OFF_GB) + (i64)b * EP * EP, EP,
              t / 5, t % 5, EP, 0,
              (u16*)(ws + OFF_ZGC) + (i64)b * EB * HEP + (i64)h * EP, HEP,
              nullptr, nullptr, pool);
}

// ===== L4 ct: CT partials = ZGcat * Ucat^T (320 blocks, K=1280 splitK4)
__global__ __launch_bounds__(256)
void ct(char* __restrict__ ws)
{
    GEMM_LDS
    const int x = blockIdx.x & 7, o = blockIdx.x >> 3;
    const int id = x * 40 + o;
    const int z = id / 20, t = id % 20, b = z >> 2, sp = z & 3;
    const u16* A = (const u16*)(ws + OFF_ZGC) + (i64)b * EB * HEP + (i64)sp * 1280;
    const u16* B = (const u16*)(ws + OFF_UCAT) + (i64)sp * 1280;
    float* C = (float*)(ws + OFF_CTP) + ((i64)(b * 4 + sp) * 20 + t) * 16384;
    gemm_body(A, HEP, B, HEP, t / 5, t % 5, 1280, 3, C, 0,
              nullptr, nullptr, pool);
}

// ===== L5 cvt2: CT reduce (80) + q->bf16 (1024 units) = 1104 blocks
__global__ __launch_bounds__(256)
void cvt2(char* __restrict__ ws, const float* __restrict__ q)
{
    const int u = blockIdx.x, tid = threadIdx.x;
    if (u < 80) {
        const int b = u / 20, t = u % 20;
        const int bx = t / 5, by = t % 5;
        const int lane = tid & 63, wid = tid >> 6;
        const int wr = wid >> 1, wc = wid & 1, g = lane >> 4, li = lane & 15;
        const float* base = (const float*)(ws + OFF_CTP) + ((i64)b * 4 * 20 + t) * 16384;
        u16* ctb = (u16*)(ws + OFF_CTB) + (i64)b * EB * EP;
        float* rb = (float*)(ws + OFF_RB) + (i64)b * EB;
#pragma unroll
        for (int fm = 0; fm < 4; ++fm)
#pragma unroll
            for (int fn = 0; fn < 4; ++fn) {
                const int fo = (fm * 4 + fn) * 1024 + tid * 4;
                f32x4 s = *(const f32x4*)(base + fo);
#pragma unroll
                for (int p = 1; p < 4; ++p) {
                    f32x4 pp = *(const f32x4*)(base + (i64)p * 20 * 16384 + fo);
                    s[0] += pp[0]; s[1] += pp[1]; s[2] += pp[2]; s[3] += pp[3];
                }
                const int row0 = bx * 128 + wr * 64 + fm * 16 + g * 4;
                const int col = by * 128 + wc * 64 + fn * 16 + li;
#pragma unroll
                for (int qq = 0; qq < 4; ++qq) {
                    const float val = s[qq] * (1.0f / 512.0f);
                    ctb[(i64)(row0 + qq) * EP + col] = f2bf(val);
                    if (col == 512) rb[row0 + qq] = val;
                }
            }
    } else {
        const i64 j = u - 80;
#pragma unroll
        for (int s = 0; s < 4; ++s)
            cvt_dev((const float4*)q, (ushort4*)(ws + OFF_QB), 1.0f,
                    j * 1024 + s * 256 + tid);
    }
}

// ===== L6 out: out[b] = q~[b] * CTb[b]^T + rb + bo (256 blocks, K=512)
__global__ __launch_bounds__(256)
void gout(char* __restrict__ ws, float* __restrict__ out,
          const float* __restrict__ bo)
{
    GEMM_LDS
    const int x = blockIdx.x & 7, o = blockIdx.x >> 3;
    const int id = x * 32 + o;
    const int b = id / 64, t = id % 64;
    gemm_body((const u16*)(ws + OFF_QB) + (i64)b * SQ * EB, EB,
              (const u16*)(ws + OFF_CTB) + (i64)b * EB * EP, EP,
              t / 4, t % 4, EB, 2,
              out + (i64)b * SQ * EB, EB,
              (const float*)(ws + OFF_RB) + (i64)b * EB, bo, pool);
}

extern "C" void kernel_launch(void* const* d_in, const int* in_sizes, int n_in,
                              void* d_out, int out_size, void* d_ws, size_t ws_size,
                              hipStream_t stream)
{
    const float* q  = (const float*)d_in[0];
    const float* k  = (const float*)d_in[1];
    const float* v  = (const float*)d_in[2];
    const float* Wq = (const float*)d_in[3];
    const float* bq = (const float*)d_in[4];
    const float* Wk = (const float*)d_in[5];
    const float* bk = (const float*)d_in[6];
    const float* Wv = (const float*)d_in[7];
    const float* bv = (const float*)d_in[8];
    const float* Wo = (const float*)d_in[9];
    const float* bo = (const float*)d_in[10];
    float* out = (float*)d_out;
    char* ws = (char*)d_ws;
    (void)in_sizes; (void)n_in; (void)out_size; (void)ws_size;

    const dim3 blk(256);

    prep<<<dim3(4992), blk, 0, stream>>>(k, v, Wq, bq, Wk, bk, Wv, bv, Wo, ws);
    stage1<<<dim3(560), blk, 0, stream>>>(ws);
    gred<<<dim3(100), blk, 0, stream>>>(ws);
    zg<<<dim3(640), blk, 0, stream>>>(ws);
    ct<<<dim3(320), blk, 0, stream>>>(ws);
    cvt2<<<dim3(1104), blk, 0, stream>>>(ws, q);
    gout<<<dim3(256), blk, 0, stream>>>(ws, out, bo);
}

// Round 11
// 223.009 us; speedup vs baseline: 7.1109x; 1.1847x over previous
//
#include <hip/hip_runtime.h>

// B=4,S=2048,E=512,H=8. Linear attention (no softmax) collapsed to GEMM chain:
//  out[b] = q~[b]*C~[b]+bo,  C~[b]=(1/512) sum_h U~[h] G~[b] Z~[h]^T
// Multi-launch, balanced units, no atomics. All GEMMs: NT 64x128 tiles
// (A 8KB + B 16KB = 24KB single-buffered LDS -> ~5 blocks/CU; grids 2x vs
// 128^2 tiles, fixing grid-starvation at 256 CUs), BK=64,
// global_load_lds(16B) pre-swizzled source + XOR-swizzled ds_read_b128,
// 16x16x32 bf16 MFMA, f32 acc.

typedef long long i64;
typedef unsigned short u16;
typedef __attribute__((ext_vector_type(8))) short bf16x8;
typedef __attribute__((ext_vector_type(4))) float f32x4;

#define EB 512
#define EP 640
#define SQ 2048
#define NB 4
#define NH 8
#define HEP 5120

// ---- workspace byte offsets (peak 69,074,944) ----
#define OFF_KT    0ll          // 10,485,760  bf16 kT [4][640][2048]   L0->L1
#define OFF_VT    10485760ll   // 10,485,760  bf16 vT                  L0->L1
#define OFF_WQT   20971520ll   //  5,242,880  bf16 WqT [8][640][512]   L0->L1
#define OFF_WKT   26214400ll   //  5,242,880                           L0->L1
#define OFF_WVT   31457280ll   //  5,242,880                           L0->L1
#define OFF_WOB   36700160ll   //  4,194,304  bf16 Wo [512][4096]      L0->L1
#define OFF_ZCAT  40894464ll   //  5,242,880  bf16 Zcat [512][5120]    L1->L3
#define OFF_UCAT  46137344ll   //  6,553,600  bf16 Ucat [640][5120]    L1->L4
#define OFF_GP    52690944ll   // 13,107,200  f32 G partials [4][2][50][8192] L1->L2
#define OFF_GB    65798144ll   //  3,276,800  bf16 Gb [4][640][640]    L2->L3
#define OFF_ZGC   0ll          // 20,971,520  bf16 ZGcat [4][512][5120] L3->L4 (alias KT+VT)
#define OFF_CTP   20971520ll   // 20,971,520  f32 CT partials [4][4][40][8192] L4->L5 (alias W*)
#define OFF_QB    0ll          //  8,388,608  bf16 q [4][2048][512]    L5->L6 (alias ZGC)
#define OFF_CTB   46137344ll   //  2,621,440  bf16 CTb [4][512][640]   L5->L6 (alias UCAT)
#define OFF_RB    48758784ll   //      8,192  f32 rb [4][512]          L5->L6

__device__ __forceinline__ u16 f2bf(float x) {
    unsigned u = __float_as_uint(x);
    return (u16)((u + 0x7fffu + ((u >> 16) & 1u)) >> 16);
}

__device__ __forceinline__ void gload16(const void* g, void* l) {
    __builtin_amdgcn_global_load_lds(
        (const __attribute__((address_space(1))) unsigned int*)g,
        (__attribute__((address_space(3))) unsigned int*)l, 16, 0, 0);
}

// ====== GEMM body: C = A*B^T, 64x128 tile, BK=64, single-buffered 24KB LDS ======
// 4 waves: wave w owns cols w*32..w*32+31 (fn 0..1), all 64 rows (fm 0..3).
// epi 0: bf16 store. epi 2: f32 store + rb[col]+bo[col]. epi 3: fragment-layout
// f32x4 partial store (8192 f32 / tile).
__device__ __forceinline__ void gemm64(
    const u16* __restrict__ A, i64 lda, const u16* __restrict__ B, i64 ldb,
    int bx, int by, int K, int epi, void* Cv, i64 ldc,
    const float* rbias, const float* bo, char* pool)
{
    char* lA = pool;            // 8 KB  (64 rows x 64 cols bf16), 8 chunks
    char* lB = pool + 8192;     // 16 KB (128 rows x 64 cols),    16 chunks
    const i64 m0 = (i64)bx * 64, n0 = (i64)by * 128;
    const int tid = threadIdx.x, lane = tid & 63, wid = tid >> 6;
    const int g = lane >> 4, li = lane & 15;

    // 24 chunks of 1KB (8 rows each); wave w stages chunks w*6..w*6+5.
    const u16* gsrc[6]; char* ldst[6];
#pragma unroll
    for (int i = 0; i < 6; ++i) {
        const int c = wid * 6 + i;
        const bool isA = c < 8;
        const int cc = isA ? c : c - 8;
        const int rr = cc * 8 + (lane >> 3);
        const int gc = ((lane & 7) ^ (rr & 7)) << 3;   // pre-swizzled col chunk
        gsrc[i] = (isA ? A + (m0 + rr) * lda : B + (n0 + rr) * ldb) + gc;
        ldst[i] = (isA ? lA + c * 1024 : lB + cc * 1024) + lane * 16;
    }

    f32x4 acc[4][2];
#pragma unroll
    for (int a_ = 0; a_ < 4; ++a_)
#pragma unroll
        for (int b_ = 0; b_ < 2; ++b_) acc[a_][b_] = (f32x4){0.f, 0.f, 0.f, 0.f};

    const int nIt = K >> 6;
    for (int it = 0; it < nIt; ++it) {
        const i64 k0 = (i64)it << 6;
#pragma unroll
        for (int i = 0; i < 6; ++i) gload16(gsrc[i] + k0, ldst[i]);
        __syncthreads();
#pragma unroll
        for (int ks = 0; ks < 2; ++ks) {
            bf16x8 af[4], bf[2];
#pragma unroll
            for (int fm = 0; fm < 4; ++fm) {
                const int row = fm * 16 + li;
                const int slot = (ks * 4 + g) ^ (row & 7);
                af[fm] = *(const bf16x8*)(lA + row * 128 + slot * 16);
            }
#pragma unroll
            for (int fn = 0; fn < 2; ++fn) {
                const int row = wid * 32 + fn * 16 + li;
                const int slot = (ks * 4 + g) ^ (row & 7);
                bf[fn] = *(const bf16x8*)(lB + row * 128 + slot * 16);
            }
#pragma unroll
            for (int fm = 0; fm < 4; ++fm)
#pragma unroll
                for (int fn = 0; fn < 2; ++fn)
                    acc[fm][fn] = __builtin_amdgcn_mfma_f32_16x16x32_bf16(
                        af[fm], bf[fn], acc[fm][fn], 0, 0, 0);
        }
        __syncthreads();
    }

    if (epi == 0) {
        u16* C = (u16*)Cv;
#pragma unroll
        for (int fm = 0; fm < 4; ++fm)
#pragma unroll
            for (int fn = 0; fn < 2; ++fn) {
                const i64 col = n0 + wid * 32 + fn * 16 + li;
#pragma unroll
                for (int q = 0; q < 4; ++q) {
                    const i64 row = m0 + fm * 16 + g * 4 + q;
                    C[row * ldc + col] = f2bf(acc[fm][fn][q]);
                }
            }
    } else if (epi == 2) {
        float* C = (float*)Cv;
#pragma unroll
        for (int fn = 0; fn < 2; ++fn) {
            const i64 col = n0 + wid * 32 + fn * 16 + li;
            const float bb = rbias[col] + bo[col];
#pragma unroll
            for (int fm = 0; fm < 4; ++fm)
#pragma unroll
                for (int q = 0; q < 4; ++q) {
                    const i64 row = m0 + fm * 16 + g * 4 + q;
                    C[row * ldc + col] = acc[fm][fn][q] + bb;
                }
        }
    } else {   // epi 3: fragment-layout partial, fully coalesced f32x4
        float* C = (float*)Cv;
#pragma unroll
        for (int fm = 0; fm < 4; ++fm)
#pragma unroll
            for (int fn = 0; fn < 2; ++fn)
                *(f32x4*)(C + (fm * 2 + fn) * 1024 + tid * 4) = acc[fm][fn];
    }
}

#define GEMM_LDS __shared__ __align__(16) char pool[24576];

// =============== transpose+aug: f32 [Sx512] -> bf16 [640xS] ===============
__device__ __forceinline__ void transpose_dev(
    const float* __restrict__ src, const float* __restrict__ aug,
    u16* __restrict__ dst, int S, int bx, int by, char* pool)
{
    const int s0 = bx * 64, e0 = by * 64;
    const int t = threadIdx.x;
    if (e0 >= EB) {
#pragma unroll
        for (int i = 0; i < 16; ++i) {
            const int idx = i * 256 + t;
            const int er = idx >> 6, sc = idx & 63;
            const int e = e0 + er;
            u16 val = 0;
            if (e == EB) val = f2bf(aug ? aug[s0 + sc] : 1.0f);
            dst[(i64)e * S + s0 + sc] = val;
        }
        return;
    }
    float (*tile)[65] = (float(*)[65])pool;
#pragma unroll
    for (int i = 0; i < 16; ++i) {
        const int idx = i * 256 + t;
        const int sr = idx >> 6, ec = idx & 63;
        tile[sr][ec] = src[(i64)(s0 + sr) * EB + e0 + ec];
    }
    __syncthreads();
#pragma unroll
    for (int i = 0; i < 16; ++i) {
        const int idx = i * 256 + t;
        const int er = idx >> 6, sc = idx & 63;
        dst[(i64)(e0 + er) * S + s0 + sc] = f2bf(tile[sc][er]);
    }
}

__device__ __forceinline__ void cvt_dev(const float4* in, ushort4* outp,
                                        float alpha, i64 i)
{
    const float4 v = in[i];
    ushort4 o;
    o.x = f2bf(v.x * alpha); o.y = f2bf(v.y * alpha);
    o.z = f2bf(v.z * alpha); o.w = f2bf(v.w * alpha);
    outp[i] = o;
}

// ===== L0 prep: transposes + Wo convert (4992 blocks)
__global__ __launch_bounds__(256)
void prep(const float* __restrict__ k, const float* __restrict__ v,
          const float* __restrict__ Wq, const float* __restrict__ bq,
          const float* __restrict__ Wk, const float* __restrict__ bk,
          const float* __restrict__ Wv, const float* __restrict__ bv,
          const float* __restrict__ Wo, char* __restrict__ ws)
{
    __shared__ __align__(16) char pool[16640];
    const int u = blockIdx.x, t = threadIdx.x;
    if (u < 1280) {               // kT
        const int bz = u / 320, r = u % 320;
        transpose_dev(k + (i64)bz * SQ * EB, nullptr,
                      (u16*)(ws + OFF_KT) + (i64)bz * EP * SQ, SQ,
                      r % 32, r / 32, pool);
    } else if (u < 2560) {        // vT
        const int l = u - 1280, bz = l / 320, r = l % 320;
        transpose_dev(v + (i64)bz * SQ * EB, nullptr,
                      (u16*)(ws + OFF_VT) + (i64)bz * EP * SQ, SQ,
                      r % 32, r / 32, pool);
    } else if (u < 3200) {        // WqT
        const int l = u - 2560, bz = l / 80, r = l % 80;
        transpose_dev(Wq + (i64)bz * EB * EB, bq + (i64)bz * EB,
                      (u16*)(ws + OFF_WQT) + (i64)bz * EP * EB, EB,
                      r % 8, r / 8, pool);
    } else if (u < 3840) {        // WkT
        const int l = u - 3200, bz = l / 80, r = l % 80;
        transpose_dev(Wk + (i64)bz * EB * EB, bk + (i64)bz * EB,
                      (u16*)(ws + OFF_WKT) + (i64)bz * EP * EB, EB,
                      r % 8, r / 8, pool);
    } else if (u < 4480) {        // WvT
        const int l = u - 3840, bz = l / 80, r = l % 80;
        transpose_dev(Wv + (i64)bz * EB * EB, bv + (i64)bz * EB,
                      (u16*)(ws + OFF_WVT) + (i64)bz * EP * EB, EB,
                      r % 8, r / 8, pool);
    } else {                      // Wo cvt (512 units x 1024 float4)
        const i64 j = u - 4480;
#pragma unroll
        for (int s = 0; s < 4; ++s)
            cvt_dev((const float4*)Wo, (ushort4*)(ws + OFF_WOB), 1.0f,
                    j * 1024 + s * 256 + t);
    }
}

// ===== L1 stage1: G splitK2 (400 units, 16it, dispatched FIRST) + U(400)/Z(320), 8it
// 1120 blocks. XCD chunking: x=bid&7, o=bid>>3 (0..139).
__global__ __launch_bounds__(256)
void stage1(char* __restrict__ ws)
{
    GEMM_LDS
    const int x = blockIdx.x & 7, o = blockIdx.x >> 3;
    if (o < 50) {                 // G split-K partial (K=1024, epi3)
        const int gu = x * 50 + o;               // 0..399
        const int b = gu / 100, sp = (gu / 50) & 1, r = gu % 50;
        const u16* A = (const u16*)(ws + OFF_KT) + (i64)b * EP * SQ + sp * 1024;
        const u16* B = (const u16*)(ws + OFF_VT) + (i64)b * EP * SQ + sp * 1024;
        float* C = (float*)(ws + OFF_GP) + ((i64)(b * 2 + sp) * 50 + r) * 8192;
        gemm64(A, SQ, B, SQ, r / 5, r % 5, 1024, 3, C, 0, nullptr, nullptr, pool);
    } else {
        const int j = x * 90 + (o - 50);         // 0..719
        if (j < 400) {            // U[h] -> Ucat col h*640 (M=640: bx 0..9)
            const int h = j / 50, r = j % 50;
            gemm64((const u16*)(ws + OFF_WQT) + (i64)h * EP * EB, EB,
                   (const u16*)(ws + OFF_WKT) + (i64)h * EP * EB, EB,
                   r / 5, r % 5, EB, 0,
                   (u16*)(ws + OFF_UCAT) + (i64)h * EP, HEP,
                   nullptr, nullptr, pool);
        } else {                  // Z[h] -> Zcat col h*640 (M=512: bx 0..7)
            const int j2 = j - 400, h = j2 / 40, r = j2 % 40;
            gemm64((const u16*)(ws + OFF_WOB) + (i64)h * EB, (i64)NH * EB,
                   (const u16*)(ws + OFF_WVT) + (i64)h * EP * EB, EB,
                   r / 5, r % 5, EB, 0,
                   (u16*)(ws + OFF_ZCAT) + (i64)h * EP, HEP,
                   nullptr, nullptr, pool);
        }
    }
}

// ===== L2 gred: reduce 2 G partials -> bf16 Gb (200 blocks)
__global__ __launch_bounds__(256)
void gred(char* __restrict__ ws)
{
    const int u = blockIdx.x;
    const int b = u / 50, t = u % 50;
    const int bx = t / 5, by = t % 5;
    const int tid = threadIdx.x, lane = tid & 63, wid = tid >> 6;
    const int g = lane >> 4, li = lane & 15;
    const float* base = (const float*)(ws + OFF_GP) + ((i64)b * 2 * 50 + t) * 8192;
    u16* gb = (u16*)(ws + OFF_GB) + (i64)b * EP * EP;
#pragma unroll
    for (int fm = 0; fm < 4; ++fm)
#pragma unroll
        for (int fn = 0; fn < 2; ++fn) {
            const int fo = (fm * 2 + fn) * 1024 + tid * 4;
            f32x4 s = *(const f32x4*)(base + fo);
            f32x4 p1 = *(const f32x4*)(base + 50 * 8192 + fo);
            s[0] += p1[0]; s[1] += p1[1]; s[2] += p1[2]; s[3] += p1[3];
            const int row0 = bx * 64 + fm * 16 + g * 4;
            const int col = by * 128 + wid * 32 + fn * 16 + li;
#pragma unroll
            for (int qq = 0; qq < 4; ++qq)
                gb[(i64)(row0 + qq) * EP + col] = f2bf(s[qq]);
        }
}

// ===== L3 zg: ZG[b,h] = Z[h] * G[b]^T (1280 blocks, K=640)
__global__ __launch_bounds__(256)
void zg(char* __restrict__ ws)
{
    GEMM_LDS
    const int x = blockIdx.x & 7, o = blockIdx.x >> 3;
    const int id = x * 160 + o;
    const int z = id / 40, t = id % 40, b = z >> 3, h = z & 7;
    gemm64((const u16*)(ws + OFF_ZCAT) + (i64)h * EP, HEP,
           (const u16*)(ws + OFF_GB) + (i64)b * EP * EP, EP,
           t / 5, t % 5, EP, 0,
           (u16*)(ws + OFF_ZGC) + (i64)b * EB * HEP + (i64)h * EP, HEP,
           nullptr, nullptr, pool);
}

// ===== L4 ct: CT partials = ZGcat * Ucat^T (640 blocks, K=1280 splitK4)
__global__ __launch_bounds__(256)
void ct(char* __restrict__ ws)
{
    GEMM_LDS
    const int x = blockIdx.x & 7, o = blockIdx.x >> 3;
    const int id = x * 80 + o;
    const int z = id / 40, t = id % 40, b = z >> 2, sp = z & 3;
    const u16* A = (const u16*)(ws + OFF_ZGC) + (i64)b * EB * HEP + (i64)sp * 1280;
    const u16* B = (const u16*)(ws + OFF_UCAT) + (i64)sp * 1280;
    float* C = (float*)(ws + OFF_CTP) + ((i64)(b * 4 + sp) * 40 + t) * 8192;
    gemm64(A, HEP, B, HEP, t / 5, t % 5, 1280, 3, C, 0,
           nullptr, nullptr, pool);
}

// ===== L5 cvt2: CT reduce (160) + q->bf16 (1024 units) = 1184 blocks
__global__ __launch_bounds__(256)
void cvt2(char* __restrict__ ws, const float* __restrict__ q)
{
    const int u = blockIdx.x, tid = threadIdx.x;
    if (u < 160) {
        const int b = u / 40, t = u % 40;
        const int bx = t / 5, by = t % 5;
        const int lane = tid & 63, wid = tid >> 6;
        const int g = lane >> 4, li = lane & 15;
        const float* base = (const float*)(ws + OFF_CTP) + ((i64)b * 4 * 40 + t) * 8192;
        u16* ctb = (u16*)(ws + OFF_CTB) + (i64)b * EB * EP;
        float* rb = (float*)(ws + OFF_RB) + (i64)b * EB;
#pragma unroll
        for (int fm = 0; fm < 4; ++fm)
#pragma unroll
            for (int fn = 0; fn < 2; ++fn) {
                const int fo = (fm * 2 + fn) * 1024 + tid * 4;
                f32x4 s = *(const f32x4*)(base + fo);
#pragma unroll
                for (int p = 1; p < 4; ++p) {
                    f32x4 pp = *(const f32x4*)(base + (i64)p * 40 * 8192 + fo);
                    s[0] += pp[0]; s[1] += pp[1]; s[2] += pp[2]; s[3] += pp[3];
                }
                const int row0 = bx * 64 + fm * 16 + g * 4;
                const int col = by * 128 + wid * 32 + fn * 16 + li;
#pragma unroll
                for (int qq = 0; qq < 4; ++qq) {
                    const float val = s[qq] * (1.0f / 512.0f);
                    ctb[(i64)(row0 + qq) * EP + col] = f2bf(val);
                    if (col == 512) rb[row0 + qq] = val;
                }
            }
    } else {
        const i64 j = u - 160;
        if (j < 1024) {
#pragma unroll
            for (int s = 0; s < 4; ++s)
                cvt_dev((const float4*)q, (ushort4*)(ws + OFF_QB), 1.0f,
                        j * 1024 + s * 256 + tid);
        }
    }
}

// ===== L6 out: out[b] = q~[b] * CTb[b]^T + rb + bo (512 blocks, K=512)
__global__ __launch_bounds__(256)
void gout(char* __restrict__ ws, float* __restrict__ out,
          const float* __restrict__ bo)
{
    GEMM_LDS
    const int x = blockIdx.x & 7, o = blockIdx.x >> 3;
    const int id = x * 64 + o;
    const int b = id / 128, t = id % 128;
    gemm64((const u16*)(ws + OFF_QB) + (i64)b * SQ * EB, EB,
           (const u16*)(ws + OFF_CTB) + (i64)b * EB * EP, EP,
           t / 4, t % 4, EB, 2,
           out + (i64)b * SQ * EB, EB,
           (const float*)(ws + OFF_RB) + (i64)b * EB, bo, pool);
}

extern "C" void kernel_launch(void* const* d_in, const int* in_sizes, int n_in,
                              void* d_out, int out_size, void* d_ws, size_t ws_size,
                              hipStream_t stream)
{
    const float* q  = (const float*)d_in[0];
    const float* k  = (const float*)d_in[1];
    const float* v  = (const float*)d_in[2];
    const float* Wq = (const float*)d_in[3];
    const float* bq = (const float*)d_in[4];
    const float* Wk = (const float*)d_in[5];
    const float* bk = (const float*)d_in[6];
    const float* Wv = (const float*)d_in[7];
    const float* bv = (const float*)d_in[8];
    const float* Wo = (const float*)d_in[9];
    const float* bo = (const float*)d_in[10];
    float* out = (float*)d_out;
    char* ws = (char*)d_ws;
    (void)in_sizes; (void)n_in; (void)out_size; (void)ws_size;

    const dim3 blk(256);

    prep<<<dim3(4992), blk, 0, stream>>>(k, v, Wq, bq, Wk, bk, Wv, bv, Wo, ws);
    stage1<<<dim3(1120), blk, 0, stream>>>(ws);
    gred<<<dim3(200), blk, 0, stream>>>(ws);
    zg<<<dim3(1280), blk, 0, stream>>>(ws);
    ct<<<dim3(640), blk, 0, stream>>>(ws);
    cvt2<<<dim3(1184), blk, 0, stream>>>(ws, q);
    gout<<<dim3(512), blk, 0, stream>>>(ws, out, bo);
}

// Round 12
// 220.312 us; speedup vs baseline: 7.1979x; 1.0122x over previous
//
#include <hip/hip_runtime.h>

// B=4,S=2048,E=512,H=8. Linear attention (no softmax) collapsed to GEMM chain:
//  out[b] = q~[b]*C~[b]+bo,  C~[b]=(1/512) sum_h U~[h] G~[b] Z~[h]^T
// Multi-launch, balanced units, no atomics. All GEMMs: NT 64x128 tiles,
// BK=128 (two 64-col K-halves per barrier, 32 MFMA/wave/iter), 48KB
// single-buffered LDS (3 blocks/CU), global_load_lds(16B) pre-swizzled
// source + XOR-swizzled ds_read_b128, 16x16x32 bf16 MFMA, f32 acc.

typedef long long i64;
typedef unsigned short u16;
typedef __attribute__((ext_vector_type(8))) short bf16x8;
typedef __attribute__((ext_vector_type(4))) float f32x4;

#define EB 512
#define EP 640
#define SQ 2048
#define NB 4
#define NH 8
#define HEP 5120

// ---- workspace byte offsets (peak 69,074,944) ----
#define OFF_KT    0ll          // 10,485,760  bf16 kT [4][640][2048]   L0->L1
#define OFF_VT    10485760ll   // 10,485,760  bf16 vT                  L0->L1
#define OFF_WQT   20971520ll   //  5,242,880  bf16 WqT [8][640][512]   L0->L1
#define OFF_WKT   26214400ll   //  5,242,880                           L0->L1
#define OFF_WVT   31457280ll   //  5,242,880                           L0->L1
#define OFF_WOB   36700160ll   //  4,194,304  bf16 Wo [512][4096]      L0->L1
#define OFF_ZCAT  40894464ll   //  5,242,880  bf16 Zcat [512][5120]    L1->L3
#define OFF_UCAT  46137344ll   //  6,553,600  bf16 Ucat [640][5120]    L1->L4
#define OFF_GP    52690944ll   // 13,107,200  f32 G partials [4][2][50][8192] L1->L2
#define OFF_GB    65798144ll   //  3,276,800  bf16 Gb [4][640][640]    L2->L3
#define OFF_ZGC   0ll          // 20,971,520  bf16 ZGcat [4][512][5120] L3->L4 (alias KT+VT)
#define OFF_CTP   20971520ll   // 20,971,520  f32 CT partials [4][4][40][8192] L4->L5 (alias W*)
#define OFF_QB    0ll          //  8,388,608  bf16 q [4][2048][512]    L5->L6 (alias ZGC)
#define OFF_CTB   46137344ll   //  2,621,440  bf16 CTb [4][512][640]   L5->L6 (alias UCAT)
#define OFF_RB    48758784ll   //      8,192  f32 rb [4][512]          L5->L6

__device__ __forceinline__ u16 f2bf(float x) {
    unsigned u = __float_as_uint(x);
    return (u16)((u + 0x7fffu + ((u >> 16) & 1u)) >> 16);
}

__device__ __forceinline__ void gload16(const void* g, void* l) {
    __builtin_amdgcn_global_load_lds(
        (const __attribute__((address_space(1))) unsigned int*)g,
        (__attribute__((address_space(3))) unsigned int*)l, 16, 0, 0);
}

// ====== GEMM body: C = A*B^T, 64x128 tile, BK=128, single-buffered 48KB LDS ======
// LDS: A half0 [0,8K), A half1 [8K,16K), B half0 [16K,32K), B half1 [32K,48K).
// 4 waves: wave w owns cols w*32..w*32+31 (fn 0..1), all 64 rows (fm 0..3).
// 48 chunks of 1KB (8 rows each); wave w stages chunks w*12..w*12+11.
// epi 0: bf16 store. epi 2: f32 store + rb[col]+bo[col]. epi 3: fragment-layout
// f32x4 partial store (8192 f32 / tile).
__device__ __forceinline__ void gemm64(
    const u16* __restrict__ A, i64 lda, const u16* __restrict__ B, i64 ldb,
    int bx, int by, int K, int epi, void* Cv, i64 ldc,
    const float* rbias, const float* bo, char* pool)
{
    const i64 m0 = (i64)bx * 64, n0 = (i64)by * 128;
    const int tid = threadIdx.x, lane = tid & 63, wid = tid >> 6;
    const int g = lane >> 4, li = lane & 15;

    const u16* gsrc[12]; char* ldst[12];
#pragma unroll
    for (int i = 0; i < 12; ++i) {
        const int c = wid * 12 + i;
        const bool isA = c < 16;
        const int half = isA ? (c >> 3) : ((c - 16) >> 4);
        const int cc = isA ? (c & 7) : ((c - 16) & 15);
        const int rr = cc * 8 + (lane >> 3);
        const int gc = (half << 6) + (((lane & 7) ^ (rr & 7)) << 3);
        gsrc[i] = (isA ? A + (m0 + rr) * lda : B + (n0 + rr) * ldb) + gc;
        ldst[i] = pool + (isA ? half * 8192 : 16384 + half * 16384)
                       + cc * 1024 + lane * 16;
    }

    f32x4 acc[4][2];
#pragma unroll
    for (int a_ = 0; a_ < 4; ++a_)
#pragma unroll
        for (int b_ = 0; b_ < 2; ++b_) acc[a_][b_] = (f32x4){0.f, 0.f, 0.f, 0.f};

    const int nIt = K >> 7;
    for (int it = 0; it < nIt; ++it) {
        const i64 k0 = (i64)it << 7;
#pragma unroll
        for (int i = 0; i < 12; ++i) gload16(gsrc[i] + k0, ldst[i]);
        __syncthreads();
#pragma unroll
        for (int ks = 0; ks < 4; ++ks) {
            const int h = ks >> 1, s2 = ks & 1;
            bf16x8 af[4], bf[2];
#pragma unroll
            for (int fm = 0; fm < 4; ++fm) {
                const int row = fm * 16 + li;
                const int slot = (s2 * 4 + g) ^ (row & 7);
                af[fm] = *(const bf16x8*)(pool + h * 8192 + row * 128 + slot * 16);
            }
#pragma unroll
            for (int fn = 0; fn < 2; ++fn) {
                const int row = wid * 32 + fn * 16 + li;
                const int slot = (s2 * 4 + g) ^ (row & 7);
                bf[fn] = *(const bf16x8*)(pool + 16384 + h * 16384 + row * 128 + slot * 16);
            }
#pragma unroll
            for (int fm = 0; fm < 4; ++fm)
#pragma unroll
                for (int fn = 0; fn < 2; ++fn)
                    acc[fm][fn] = __builtin_amdgcn_mfma_f32_16x16x32_bf16(
                        af[fm], bf[fn], acc[fm][fn], 0, 0, 0);
        }
        __syncthreads();
    }

    if (epi == 0) {
        u16* C = (u16*)Cv;
#pragma unroll
        for (int fm = 0; fm < 4; ++fm)
#pragma unroll
            for (int fn = 0; fn < 2; ++fn) {
                const i64 col = n0 + wid * 32 + fn * 16 + li;
#pragma unroll
                for (int q = 0; q < 4; ++q) {
                    const i64 row = m0 + fm * 16 + g * 4 + q;
                    C[row * ldc + col] = f2bf(acc[fm][fn][q]);
                }
            }
    } else if (epi == 2) {
        float* C = (float*)Cv;
#pragma unroll
        for (int fn = 0; fn < 2; ++fn) {
            const i64 col = n0 + wid * 32 + fn * 16 + li;
            const float bb = rbias[col] + bo[col];
#pragma unroll
            for (int fm = 0; fm < 4; ++fm)
#pragma unroll
                for (int q = 0; q < 4; ++q) {
                    const i64 row = m0 + fm * 16 + g * 4 + q;
                    C[row * ldc + col] = acc[fm][fn][q] + bb;
                }
        }
    } else {   // epi 3: fragment-layout partial, fully coalesced f32x4
        float* C = (float*)Cv;
#pragma unroll
        for (int fm = 0; fm < 4; ++fm)
#pragma unroll
            for (int fn = 0; fn < 2; ++fn)
                *(f32x4*)(C + (fm * 2 + fn) * 1024 + tid * 4) = acc[fm][fn];
    }
}

#define GEMM_LDS __shared__ __align__(16) char pool[49152];

// =============== transpose+aug: f32 [Sx512] -> bf16 [640xS] ===============
__device__ __forceinline__ void transpose_dev(
    const float* __restrict__ src, const float* __restrict__ aug,
    u16* __restrict__ dst, int S, int bx, int by, char* pool)
{
    const int s0 = bx * 64, e0 = by * 64;
    const int t = threadIdx.x;
    if (e0 >= EB) {
#pragma unroll
        for (int i = 0; i < 16; ++i) {
            const int idx = i * 256 + t;
            const int er = idx >> 6, sc = idx & 63;
            const int e = e0 + er;
            u16 val = 0;
            if (e == EB) val = f2bf(aug ? aug[s0 + sc] : 1.0f);
            dst[(i64)e * S + s0 + sc] = val;
        }
        return;
    }
    float (*tile)[65] = (float(*)[65])pool;
#pragma unroll
    for (int i = 0; i < 16; ++i) {
        const int idx = i * 256 + t;
        const int sr = idx >> 6, ec = idx & 63;
        tile[sr][ec] = src[(i64)(s0 + sr) * EB + e0 + ec];
    }
    __syncthreads();
#pragma unroll
    for (int i = 0; i < 16; ++i) {
        const int idx = i * 256 + t;
        const int er = idx >> 6, sc = idx & 63;
        dst[(i64)(e0 + er) * S + s0 + sc] = f2bf(tile[sc][er]);
    }
}

__device__ __forceinline__ void cvt_dev(const float4* in, ushort4* outp,
                                        float alpha, i64 i)
{
    const float4 v = in[i];
    ushort4 o;
    o.x = f2bf(v.x * alpha); o.y = f2bf(v.y * alpha);
    o.z = f2bf(v.z * alpha); o.w = f2bf(v.w * alpha);
    outp[i] = o;
}

// ===== L0 prep: transposes + Wo convert (4992 blocks)
__global__ __launch_bounds__(256)
void prep(const float* __restrict__ k, const float* __restrict__ v,
          const float* __restrict__ Wq, const float* __restrict__ bq,
          const float* __restrict__ Wk, const float* __restrict__ bk,
          const float* __restrict__ Wv, const float* __restrict__ bv,
          const float* __restrict__ Wo, char* __restrict__ ws)
{
    __shared__ __align__(16) char pool[16640];
    const int u = blockIdx.x, t = threadIdx.x;
    if (u < 1280) {               // kT
        const int bz = u / 320, r = u % 320;
        transpose_dev(k + (i64)bz * SQ * EB, nullptr,
                      (u16*)(ws + OFF_KT) + (i64)bz * EP * SQ, SQ,
                      r % 32, r / 32, pool);
    } else if (u < 2560) {        // vT
        const int l = u - 1280, bz = l / 320, r = l % 320;
        transpose_dev(v + (i64)bz * SQ * EB, nullptr,
                      (u16*)(ws + OFF_VT) + (i64)bz * EP * SQ, SQ,
                      r % 32, r / 32, pool);
    } else if (u < 3200) {        // WqT
        const int l = u - 2560, bz = l / 80, r = l % 80;
        transpose_dev(Wq + (i64)bz * EB * EB, bq + (i64)bz * EB,
                      (u16*)(ws + OFF_WQT) + (i64)bz * EP * EB, EB,
                      r % 8, r / 8, pool);
    } else if (u < 3840) {        // WkT
        const int l = u - 3200, bz = l / 80, r = l % 80;
        transpose_dev(Wk + (i64)bz * EB * EB, bk + (i64)bz * EB,
                      (u16*)(ws + OFF_WKT) + (i64)bz * EP * EB, EB,
                      r % 8, r / 8, pool);
    } else if (u < 4480) {        // WvT
        const int l = u - 3840, bz = l / 80, r = l % 80;
        transpose_dev(Wv + (i64)bz * EB * EB, bv + (i64)bz * EB,
                      (u16*)(ws + OFF_WVT) + (i64)bz * EP * EB, EB,
                      r % 8, r / 8, pool);
    } else {                      // Wo cvt (512 units x 1024 float4)
        const i64 j = u - 4480;
#pragma unroll
        for (int s = 0; s < 4; ++s)
            cvt_dev((const float4*)Wo, (ushort4*)(ws + OFF_WOB), 1.0f,
                    j * 1024 + s * 256 + t);
    }
}

// ===== L1 stage1: G splitK2 (400 units, 8it, dispatched FIRST) + U(400)/Z(320), 4it
// 1120 blocks. XCD chunking: x=bid&7, o=bid>>3 (0..139).
__global__ __launch_bounds__(256)
void stage1(char* __restrict__ ws)
{
    GEMM_LDS
    const int x = blockIdx.x & 7, o = blockIdx.x >> 3;
    if (o < 50) {                 // G split-K partial (K=1024, epi3)
        const int gu = x * 50 + o;               // 0..399
        const int b = gu / 100, sp = (gu / 50) & 1, r = gu % 50;
        const u16* A = (const u16*)(ws + OFF_KT) + (i64)b * EP * SQ + sp * 1024;
        const u16* B = (const u16*)(ws + OFF_VT) + (i64)b * EP * SQ + sp * 1024;
        float* C = (float*)(ws + OFF_GP) + ((i64)(b * 2 + sp) * 50 + r) * 8192;
        gemm64(A, SQ, B, SQ, r / 5, r % 5, 1024, 3, C, 0, nullptr, nullptr, pool);
    } else {
        const int j = x * 90 + (o - 50);         // 0..719
        if (j < 400) {            // U[h] -> Ucat col h*640 (M=640: bx 0..9)
            const int h = j / 50, r = j % 50;
            gemm64((const u16*)(ws + OFF_WQT) + (i64)h * EP * EB, EB,
                   (const u16*)(ws + OFF_WKT) + (i64)h * EP * EB, EB,
                   r / 5, r % 5, EB, 0,
                   (u16*)(ws + OFF_UCAT) + (i64)h * EP, HEP,
                   nullptr, nullptr, pool);
        } else {                  // Z[h] -> Zcat col h*640 (M=512: bx 0..7)
            const int j2 = j - 400, h = j2 / 40, r = j2 % 40;
            gemm64((const u16*)(ws + OFF_WOB) + (i64)h * EB, (i64)NH * EB,
                   (const u16*)(ws + OFF_WVT) + (i64)h * EP * EB, EB,
                   r / 5, r % 5, EB, 0,
                   (u16*)(ws + OFF_ZCAT) + (i64)h * EP, HEP,
                   nullptr, nullptr, pool);
        }
    }
}

// ===== L2 gred: reduce 2 G partials -> bf16 Gb (200 blocks)
__global__ __launch_bounds__(256)
void gred(char* __restrict__ ws)
{
    const int u = blockIdx.x;
    const int b = u / 50, t = u % 50;
    const int bx = t / 5, by = t % 5;
    const int tid = threadIdx.x, lane = tid & 63, wid = tid >> 6;
    const int g = lane >> 4, li = lane & 15;
    const float* base = (const float*)(ws + OFF_GP) + ((i64)b * 2 * 50 + t) * 8192;
    u16* gb = (u16*)(ws + OFF_GB) + (i64)b * EP * EP;
#pragma unroll
    for (int fm = 0; fm < 4; ++fm)
#pragma unroll
        for (int fn = 0; fn < 2; ++fn) {
            const int fo = (fm * 2 + fn) * 1024 + tid * 4;
            f32x4 s = *(const f32x4*)(base + fo);
            f32x4 p1 = *(const f32x4*)(base + 50 * 8192 + fo);
            s[0] += p1[0]; s[1] += p1[1]; s[2] += p1[2]; s[3] += p1[3];
            const int row0 = bx * 64 + fm * 16 + g * 4;
            const int col = by * 128 + wid * 32 + fn * 16 + li;
#pragma unroll
            for (int qq = 0; qq < 4; ++qq)
                gb[(i64)(row0 + qq) * EP + col] = f2bf(s[qq]);
        }
}

// ===== L3 zg: ZG[b,h] = Z[h] * G[b]^T (1280 blocks, K=640)
__global__ __launch_bounds__(256)
void zg(char* __restrict__ ws)
{
    GEMM_LDS
    const int x = blockIdx.x & 7, o = blockIdx.x >> 3;
    const int id = x * 160 + o;
    const int z = id / 40, t = id % 40, b = z >> 3, h = z & 7;
    gemm64((const u16*)(ws + OFF_ZCAT) + (i64)h * EP, HEP,
           (const u16*)(ws + OFF_GB) + (i64)b * EP * EP, EP,
           t / 5, t % 5, EP, 0,
           (u16*)(ws + OFF_ZGC) + (i64)b * EB * HEP + (i64)h * EP, HEP,
           nullptr, nullptr, pool);
}

// ===== L4 ct: CT partials = ZGcat * Ucat^T (640 blocks, K=1280 splitK4)
__global__ __launch_bounds__(256)
void ct(char* __restrict__ ws)
{
    GEMM_LDS
    const int x = blockIdx.x & 7, o = blockIdx.x >> 3;
    const int id = x * 80 + o;
    const int z = id / 40, t = id % 40, b = z >> 2, sp = z & 3;
    const u16* A = (const u16*)(ws + OFF_ZGC) + (i64)b * EB * HEP + (i64)sp * 1280;
    const u16* B = (const u16*)(ws + OFF_UCAT) + (i64)sp * 1280;
    float* C = (float*)(ws + OFF_CTP) + ((i64)(b * 4 + sp) * 40 + t) * 8192;
    gemm64(A, HEP, B, HEP, t / 5, t % 5, 1280, 3, C, 0,
           nullptr, nullptr, pool);
}

// ===== L5 cvt2: CT reduce (160) + q->bf16 (1024 units) = 1184 blocks
__global__ __launch_bounds__(256)
void cvt2(char* __restrict__ ws, const float* __restrict__ q)
{
    const int u = blockIdx.x, tid = threadIdx.x;
    if (u < 160) {
        const int b = u / 40, t = u % 40;
        const int bx = t / 5, by = t % 5;
        const int lane = tid & 63, wid = tid >> 6;
        const int g = lane >> 4, li = lane & 15;
        const float* base = (const float*)(ws + OFF_CTP) + ((i64)b * 4 * 40 + t) * 8192;
        u16* ctb = (u16*)(ws + OFF_CTB) + (i64)b * EB * EP;
        float* rb = (float*)(ws + OFF_RB) + (i64)b * EB;
#pragma unroll
        for (int fm = 0; fm < 4; ++fm)
#pragma unroll
            for (int fn = 0; fn < 2; ++fn) {
                const int fo = (fm * 2 + fn) * 1024 + tid * 4;
                f32x4 s = *(const f32x4*)(base + fo);
#pragma unroll
                for (int p = 1; p < 4; ++p) {
                    f32x4 pp = *(const f32x4*)(base + (i64)p * 40 * 8192 + fo);
                    s[0] += pp[0]; s[1] += pp[1]; s[2] += pp[2]; s[3] += pp[3];
                }
                const int row0 = bx * 64 + fm * 16 + g * 4;
                const int col = by * 128 + wid * 32 + fn * 16 + li;
#pragma unroll
                for (int qq = 0; qq < 4; ++qq) {
                    const float val = s[qq] * (1.0f / 512.0f);
                    ctb[(i64)(row0 + qq) * EP + col] = f2bf(val);
                    if (col == 512) rb[row0 + qq] = val;
                }
            }
    } else {
        const i64 j = u - 160;
        if (j < 1024) {
#pragma unroll
            for (int s = 0; s < 4; ++s)
                cvt_dev((const float4*)q, (ushort4*)(ws + OFF_QB), 1.0f,
                        j * 1024 + s * 256 + tid);
        }
    }
}

// ===== L6 out: out[b] = q~[b] * CTb[b]^T + rb + bo (512 blocks, K=512)
__global__ __launch_bounds__(256)
void gout(char* __restrict__ ws, float* __restrict__ out,
          const float* __restrict__ bo)
{
    GEMM_LDS
    const int x = blockIdx.x & 7, o = blockIdx.x >> 3;
    const int id = x * 64 + o;
    const int b = id / 128, t = id % 128;
    gemm64((const u16*)(ws + OFF_QB) + (i64)b * SQ * EB, EB,
           (const u16*)(ws + OFF_CTB) + (i64)b * EB * EP, EP,
           t / 4, t % 4, EB, 2,
           out + (i64)b * SQ * EB, EB,
           (const float*)(ws + OFF_RB) + (i64)b * EB, bo, pool);
}

extern "C" void kernel_launch(void* const* d_in, const int* in_sizes, int n_in,
                              void* d_out, int out_size, void* d_ws, size_t ws_size,
                              hipStream_t stream)
{
    const float* q  = (const float*)d_in[0];
    const float* k  = (const float*)d_in[1];
    const float* v  = (const float*)d_in[2];
    const float* Wq = (const float*)d_in[3];
    const float* bq = (const float*)d_in[4];
    const float* Wk = (const float*)d_in[5];
    const float* bk = (const float*)d_in[6];
    const float* Wv = (const float*)d_in[7];
    const float* bv = (const float*)d_in[8];
    const float* Wo = (const float*)d_in[9];
    const float* bo = (const float*)d_in[10];
    float* out = (float*)d_out;
    char* ws = (char*)d_ws;
    (void)in_sizes; (void)n_in; (void)out_size; (void)ws_size;

    const dim3 blk(256);

    prep<<<dim3(4992), blk, 0, stream>>>(k, v, Wq, bq, Wk, bk, Wv, bv, Wo, ws);
    stage1<<<dim3(1120), blk, 0, stream>>>(ws);
    gred<<<dim3(200), blk, 0, stream>>>(ws);
    zg<<<dim3(1280), blk, 0, stream>>>(ws);
    ct<<<dim3(640), blk, 0, stream>>>(ws);
    cvt2<<<dim3(1184), blk, 0, stream>>>(ws, q);
    gout<<<dim3(512), blk, 0, stream>>>(ws, out, bo);
}